// Round 1
// baseline (908.592 us; speedup 1.0000x reference)
//
#include <hip/hip_runtime.h>
#include <stdint.h>

// ---------------------------------------------------------------------------
// Problem constants: B=4, S=2048, D=2048, H=16, KVH=8, HD=128, N_REP=2
// ---------------------------------------------------------------------------
#define SEQ   2048
#define DIM   2048
#define NH    16
#define NKVH  8
#define HDIM  128
#define MTOT  8192      // B*S
#define LOG2E 1.44269504088896340736f

typedef short bf16x8 __attribute__((ext_vector_type(8)));   // 8 bf16 = 4 VGPRs
typedef float f32x4  __attribute__((ext_vector_type(4)));
typedef unsigned short us4 __attribute__((ext_vector_type(4)));

#define MFMA(a, b, c) __builtin_amdgcn_mfma_f32_16x16x32_bf16((a), (b), (c), 0, 0, 0)

__device__ inline unsigned short f2bf(float f) {
    unsigned u = __builtin_bit_cast(unsigned, f);
    u = (u + 0x7FFFu + ((u >> 16) & 1u)) >> 16;   // RNE
    return (unsigned short)u;
}

__device__ inline void stage16(const void* g, void* l) {
    // async global->LDS, 16B/lane; LDS dest = wave-uniform base + lane*16
    __builtin_amdgcn_global_load_lds(
        (const __attribute__((address_space(1))) void*)g,
        (__attribute__((address_space(3))) void*)l,
        16, 0, 0);
}

// ---------------------------------------------------------------------------
// Prep: x f32 -> bf16
// ---------------------------------------------------------------------------
__global__ void conv_x(const float* __restrict__ x, unsigned short* __restrict__ xb) {
    long i = ((long)blockIdx.x * 256 + threadIdx.x) * 4;
    float4 v = *(const float4*)(x + i);
    us4 o = { f2bf(v.x), f2bf(v.y), f2bf(v.z), f2bf(v.w) };
    *(us4*)(xb + i) = o;
}

// ---------------------------------------------------------------------------
// Prep: weight (K=2048 rows x N cols, f32) -> transposed bf16 [N][2048]
// ---------------------------------------------------------------------------
__global__ void transpose_w(const float* __restrict__ in, unsigned short* __restrict__ out,
                            int N, int row_off) {
    __shared__ float t[32][33];
    int tx = threadIdx.x, ty = threadIdx.y;
    int n0 = blockIdx.x * 32, k0 = blockIdx.y * 32;
    for (int i = 0; i < 4; i++)
        t[ty + i * 8][tx] = in[(long)(k0 + ty + i * 8) * N + n0 + tx];
    __syncthreads();
    for (int i = 0; i < 4; i++)
        out[(long)(row_off + n0 + ty + i * 8) * 2048 + k0 + tx] = f2bf(t[tx][ty + i * 8]);
}

// ---------------------------------------------------------------------------
// Prep: V (b,kvh,s,hd) bf16 -> V^T (b,kvh,hd,s) bf16
// ---------------------------------------------------------------------------
__global__ void transpose_v(const unsigned short* __restrict__ v, unsigned short* __restrict__ vt) {
    __shared__ unsigned short t[32][33];
    int tx = threadIdx.x, ty = threadIdx.y;
    int d0 = blockIdx.x * 32, s0 = blockIdx.y * 32, bk = blockIdx.z;
    const unsigned short* vin = v + (long)bk * SEQ * HDIM;
    unsigned short* vo = vt + (long)bk * HDIM * SEQ;
    for (int i = 0; i < 4; i++)
        t[ty + i * 8][tx] = vin[(long)(s0 + ty + i * 8) * HDIM + d0 + tx];
    __syncthreads();
    for (int i = 0; i < 4; i++)
        vo[(long)(d0 + ty + i * 8) * SEQ + s0 + tx] = t[tx][ty + i * 8];
}

// ---------------------------------------------------------------------------
// QKV GEMM: C[8192 x 4096] = xb[8192 x 2048] * W, W given as Wt[N][K].
// 128x128 tile, BK=32, 4 waves each 4x4 of 16x16x32 MFMA.
// Epilogue: RoPE on q/k columns, scatter to q (b,h,s,d), k/v (b,kvh,s,d) bf16.
// ---------------------------------------------------------------------------
__launch_bounds__(256, 2)
__global__ void qkv_gemm(const unsigned short* __restrict__ xb,
                         const unsigned short* __restrict__ wt,
                         const float* __restrict__ pcos, const float* __restrict__ psin,
                         unsigned short* __restrict__ qb, unsigned short* __restrict__ kbuf,
                         unsigned short* __restrict__ vbuf) {
    constexpr int K = DIM;
    __shared__ __align__(16) unsigned short As[128 * 32];
    __shared__ __align__(16) unsigned short Bs[128 * 32];
    const int tid = threadIdx.x;
    const int m0 = blockIdx.y * 128;
    const int n0 = blockIdx.x * 128;
    const int w = tid >> 6, lane = tid & 63, qq = lane >> 4, ln = lane & 15;
    const int wm = w >> 1, wn = w & 1;

    f32x4 acc[4][4] = {};

    const int arow = tid >> 2;
    const int acol = (tid & 3) * 8;
    const unsigned short* ag = xb + (long)(m0 + arow) * K + acol;
    const unsigned short* bg = wt + (long)(n0 + arow) * K + acol;
    unsigned short* al = As + tid * 8;
    unsigned short* bl = Bs + tid * 8;

    for (int kk = 0; kk < K; kk += 32) {
        __syncthreads();
        stage16(ag + kk, al);
        stage16(ag + kk + 64 * K, al + 2048);
        stage16(bg + kk, bl);
        stage16(bg + kk + 64 * K, bl + 2048);
        __syncthreads();
        bf16x8 a[4], b[4];
        for (int mt = 0; mt < 4; mt++)
            a[mt] = *(const bf16x8*)&As[(wm * 64 + mt * 16 + ln) * 32 + qq * 8];
        for (int nt = 0; nt < 4; nt++)
            b[nt] = *(const bf16x8*)&Bs[(wn * 64 + nt * 16 + ln) * 32 + qq * 8];
        for (int mt = 0; mt < 4; mt++)
            for (int nt = 0; nt < 4; nt++)
                acc[mt][nt] = MFMA(a[mt], b[nt], acc[mt][nt]);
    }

    for (int mt = 0; mt < 4; mt++) {
        for (int nt = 0; nt < 4; nt++) {
            int n = n0 + wn * 64 + nt * 16 + ln;
            for (int r = 0; r < 4; r++) {
                int m = m0 + wm * 64 + mt * 16 + qq * 4 + r;
                int b_ = m >> 11, s = m & (SEQ - 1);
                float v = acc[mt][nt][r];
                float p = __shfl_xor(v, 1);      // partner column d^1 (same rows)
                int d = n & (HDIM - 1);
                if (n < 3072) {                   // RoPE for q and k
                    int i = d >> 1;
                    float c = pcos[s * 64 + i], sn = psin[s * 64 + i];
                    v = (d & 1) ? (p * sn + v * c) : (v * c - p * sn);
                }
                unsigned short bfv = f2bf(v);
                if (n < 2048) {
                    int h = n >> 7;
                    qb[((long)(b_ * NH + h) * SEQ + s) * HDIM + d] = bfv;
                } else if (n < 3072) {
                    int kv = (n - 2048) >> 7;
                    kbuf[((long)(b_ * NKVH + kv) * SEQ + s) * HDIM + d] = bfv;
                } else {
                    int kv = (n - 3072) >> 7;
                    vbuf[((long)(b_ * NKVH + kv) * SEQ + s) * HDIM + d] = bfv;
                }
            }
        }
    }
}

// ---------------------------------------------------------------------------
// Flash attention (causal, GQA). Block = (qt, h, b), 256 thr = 4 waves,
// wave w owns q-rows [w*32, w*32+32). K-tile/P share one 32KB LDS buffer,
// V^T tile in another. Online softmax state per (mt, r) row.
// ---------------------------------------------------------------------------
__launch_bounds__(256, 2)
__global__ void flash(const unsigned short* __restrict__ qb,
                      const unsigned short* __restrict__ kb,
                      const unsigned short* __restrict__ vtb,
                      unsigned short* __restrict__ aout) {
    __shared__ __align__(16) unsigned short KPs[128 * 128];   // K tile, then P
    __shared__ __align__(16) unsigned short Vts[128 * 128];   // V^T tile [hd][key]
    const int tid = threadIdx.x;
    const int w = tid >> 6, lane = tid & 63, qq = lane >> 4, ln = lane & 15;
    const int qt = blockIdx.x, h = blockIdx.y, b = blockIdx.z;
    const int kv = h >> 1;
    const int q0 = qt * 128;
    const float scale = 0.088388347648318447f;   // 1/sqrt(128)

    // Q fragments in registers: A-layout, rows w*32+mt*16+ln, k = ks*32+qq*8
    const unsigned short* qptr = qb + (long)(b * NH + h) * SEQ * HDIM;
    bf16x8 qf[2][4];
    for (int mt = 0; mt < 2; mt++)
        for (int ks = 0; ks < 4; ks++)
            qf[mt][ks] = *(const bf16x8*)&qptr[(long)(q0 + w * 32 + mt * 16 + ln) * HDIM + ks * 32 + qq * 8];

    float mst[2][4], lst[2][4];
    for (int mt = 0; mt < 2; mt++)
        for (int r = 0; r < 4; r++) { mst[mt][r] = -1e30f; lst[mt][r] = 0.f; }
    f32x4 oacc[2][8] = {};

    const unsigned short* kbase = kb + (long)(b * NKVH + kv) * SEQ * HDIM;
    const unsigned short* vbase = vtb + (long)(b * NKVH + kv) * HDIM * SEQ;
    unsigned short* kl = KPs + tid * 8;
    unsigned short* vl = Vts + tid * 8;

    for (int kt = 0; kt <= qt; kt++) {
        const int k0 = kt * 128;
        __syncthreads();    // prior iter done reading LDS
        // stage K [key][hd] and V^T [hd][key]: 2048 16B-units each, 8 rounds
        for (int r = 0; r < 8; r++) {
            int u = r * 256 + tid;
            stage16(kbase + (long)(k0 + (u >> 4)) * HDIM + (u & 15) * 8, kl + r * 2048);
            stage16(vbase + (long)(u >> 4) * SEQ + k0 + (u & 15) * 8, vl + r * 2048);
        }
        __syncthreads();

        // S = Q K^T   (per wave: 32 x 128)
        f32x4 sacc[2][8] = {};
        for (int ks = 0; ks < 4; ks++) {
            for (int nt = 0; nt < 8; nt++) {
                bf16x8 bf = *(const bf16x8*)&KPs[(nt * 16 + ln) * 128 + ks * 32 + qq * 8];
                sacc[0][nt] = MFMA(qf[0][ks], bf, sacc[0][nt]);
                sacc[1][nt] = MFMA(qf[1][ks], bf, sacc[1][nt]);
            }
        }

        // scale + causal mask + online softmax
        const bool diag = (kt == qt);
        for (int mt = 0; mt < 2; mt++) {
            for (int r = 0; r < 4; r++) {
                int qpos = q0 + w * 32 + mt * 16 + qq * 4 + r;
                float mx = -1e30f;
                for (int nt = 0; nt < 8; nt++) {
                    float v = sacc[mt][nt][r] * scale;
                    if (diag && (k0 + nt * 16 + ln > qpos)) v = -1e30f;
                    sacc[mt][nt][r] = v;
                    mx = fmaxf(mx, v);
                }
                for (int off = 1; off < 16; off <<= 1) mx = fmaxf(mx, __shfl_xor(mx, off));
                float mnew = fmaxf(mst[mt][r], mx);
                float alpha = exp2f((mst[mt][r] - mnew) * LOG2E);
                float rs = 0.f;
                for (int nt = 0; nt < 8; nt++) {
                    float p = exp2f((sacc[mt][nt][r] - mnew) * LOG2E);
                    sacc[mt][nt][r] = p;
                    rs += p;
                }
                for (int off = 1; off < 16; off <<= 1) rs += __shfl_xor(rs, off);
                lst[mt][r] = lst[mt][r] * alpha + rs;
                mst[mt][r] = mnew;
                for (int nt = 0; nt < 8; nt++) oacc[mt][nt][r] *= alpha;
            }
        }

        // P -> LDS (reuse K region). Barrier: all waves done reading K tile.
        __syncthreads();
        for (int mt = 0; mt < 2; mt++)
            for (int nt = 0; nt < 8; nt++)
                for (int r = 0; r < 4; r++)
                    KPs[(w * 32 + mt * 16 + qq * 4 + r) * 128 + nt * 16 + ln] = f2bf(sacc[mt][nt][r]);

        // O += P V   (same-wave rows: no barrier needed before own-row reads)
        for (int ks = 0; ks < 4; ks++) {
            bf16x8 a0 = *(const bf16x8*)&KPs[(w * 32 + ln) * 128 + ks * 32 + qq * 8];
            bf16x8 a1 = *(const bf16x8*)&KPs[(w * 32 + 16 + ln) * 128 + ks * 32 + qq * 8];
            for (int nt = 0; nt < 8; nt++) {
                bf16x8 bf = *(const bf16x8*)&Vts[(nt * 16 + ln) * 128 + ks * 32 + qq * 8];
                oacc[0][nt] = MFMA(a0, bf, oacc[0][nt]);
                oacc[1][nt] = MFMA(a1, bf, oacc[1][nt]);
            }
        }
    }

    // epilogue: O / l -> attn_out (b, s, h*128 + d) bf16
    for (int mt = 0; mt < 2; mt++)
        for (int r = 0; r < 4; r++) {
            int srow = q0 + w * 32 + mt * 16 + qq * 4 + r;
            float inv = 1.f / lst[mt][r];
            for (int nt = 0; nt < 8; nt++) {
                int d = nt * 16 + ln;
                aout[((long)(b * SEQ) + srow) * DIM + h * HDIM + d] = f2bf(oacc[mt][nt][r] * inv);
            }
        }
}

// ---------------------------------------------------------------------------
// Output GEMM: d_out[8192 x 2048] f32 = attn[8192 x 2048] * wo, wo as Wt[N][K]
// ---------------------------------------------------------------------------
__launch_bounds__(256, 2)
__global__ void out_gemm(const unsigned short* __restrict__ ab,
                         const unsigned short* __restrict__ wt,
                         float* __restrict__ out) {
    constexpr int K = DIM;
    __shared__ __align__(16) unsigned short As[128 * 32];
    __shared__ __align__(16) unsigned short Bs[128 * 32];
    const int tid = threadIdx.x;
    const int m0 = blockIdx.y * 128;
    const int n0 = blockIdx.x * 128;
    const int w = tid >> 6, lane = tid & 63, qq = lane >> 4, ln = lane & 15;
    const int wm = w >> 1, wn = w & 1;

    f32x4 acc[4][4] = {};

    const int arow = tid >> 2;
    const int acol = (tid & 3) * 8;
    const unsigned short* ag = ab + (long)(m0 + arow) * K + acol;
    const unsigned short* bg = wt + (long)(n0 + arow) * K + acol;
    unsigned short* al = As + tid * 8;
    unsigned short* bl = Bs + tid * 8;

    for (int kk = 0; kk < K; kk += 32) {
        __syncthreads();
        stage16(ag + kk, al);
        stage16(ag + kk + 64 * K, al + 2048);
        stage16(bg + kk, bl);
        stage16(bg + kk + 64 * K, bl + 2048);
        __syncthreads();
        bf16x8 a[4], b[4];
        for (int mt = 0; mt < 4; mt++)
            a[mt] = *(const bf16x8*)&As[(wm * 64 + mt * 16 + ln) * 32 + qq * 8];
        for (int nt = 0; nt < 4; nt++)
            b[nt] = *(const bf16x8*)&Bs[(wn * 64 + nt * 16 + ln) * 32 + qq * 8];
        for (int mt = 0; mt < 4; mt++)
            for (int nt = 0; nt < 4; nt++)
                acc[mt][nt] = MFMA(a[mt], b[nt], acc[mt][nt]);
    }

    for (int mt = 0; mt < 4; mt++)
        for (int nt = 0; nt < 4; nt++) {
            int n = n0 + wn * 64 + nt * 16 + ln;
            for (int r = 0; r < 4; r++) {
                int m = m0 + wm * 64 + mt * 16 + qq * 4 + r;
                out[(long)m * DIM + n] = acc[mt][nt][r];
            }
        }
}

// ---------------------------------------------------------------------------
// Workspace layout (bytes):
//   xb      @ 0          33,554,432   (8192x2048 bf16)
//   wqkv_t  @ 33554432   16,777,216   (4096x2048 bf16, q|k|v transposed)
//   wo_t    @ 50331648    8,388,608   (2048x2048 bf16)
//   q       @ 58720256   33,554,432   (b,h,s,d bf16)
//   k       @ 92274688   16,777,216   (b,kvh,s,d bf16)
//   v       @ 109051904  16,777,216   (b,kvh,s,d bf16)
//   v_t     @ 125829120  16,777,216   (b,kvh,d,s bf16)
//   attn    @ 142606336  33,554,432   (8192x2048 bf16)
//   total   176,160,768
// ---------------------------------------------------------------------------
extern "C" void kernel_launch(void* const* d_in, const int* in_sizes, int n_in,
                              void* d_out, int out_size, void* d_ws, size_t ws_size,
                              hipStream_t stream) {
    const float* x    = (const float*)d_in[0];
    const float* wq   = (const float*)d_in[1];
    const float* wk   = (const float*)d_in[2];
    const float* wv   = (const float*)d_in[3];
    const float* wo   = (const float*)d_in[4];
    const float* pcos = (const float*)d_in[5];
    const float* psin = (const float*)d_in[6];
    float* out = (float*)d_out;

    char* ws = (char*)d_ws;
    unsigned short* xb    = (unsigned short*)(ws);
    unsigned short* wqkvt = (unsigned short*)(ws + 33554432L);
    unsigned short* wot   = (unsigned short*)(ws + 50331648L);
    unsigned short* qbuf  = (unsigned short*)(ws + 58720256L);
    unsigned short* kbuf  = (unsigned short*)(ws + 92274688L);
    unsigned short* vbuf  = (unsigned short*)(ws + 109051904L);
    unsigned short* vtb   = (unsigned short*)(ws + 125829120L);
    unsigned short* aout  = (unsigned short*)(ws + 142606336L);

    conv_x<<<16384, 256, 0, stream>>>(x, xb);
    transpose_w<<<dim3(64, 64), dim3(32, 8), 0, stream>>>(wq, wqkvt, 2048, 0);
    transpose_w<<<dim3(32, 64), dim3(32, 8), 0, stream>>>(wk, wqkvt, 1024, 2048);
    transpose_w<<<dim3(32, 64), dim3(32, 8), 0, stream>>>(wv, wqkvt, 1024, 3072);
    transpose_w<<<dim3(64, 64), dim3(32, 8), 0, stream>>>(wo, wot, 2048, 0);

    qkv_gemm<<<dim3(32, 64), 256, 0, stream>>>(xb, wqkvt, pcos, psin, qbuf, kbuf, vbuf);
    transpose_v<<<dim3(4, 64, 32), dim3(32, 8), 0, stream>>>(vbuf, vtb);
    flash<<<dim3(16, 16, 4), 256, 0, stream>>>(qbuf, kbuf, vtb, aout);
    out_gemm<<<dim3(16, 64), 256, 0, stream>>>(aout, wot, out);
}

// Round 2
// 694.996 us; speedup vs baseline: 1.3073x; 1.3073x over previous
//
#include <hip/hip_runtime.h>
#include <stdint.h>

// ---------------------------------------------------------------------------
// Problem constants: B=4, S=2048, D=2048, H=16, KVH=8, HD=128, N_REP=2
// ---------------------------------------------------------------------------
#define SEQ   2048
#define DIM   2048
#define NH    16
#define NKVH  8
#define HDIM  128
#define MTOT  8192      // B*S
#define LOG2E 1.44269504088896340736f

typedef short bf16x8 __attribute__((ext_vector_type(8)));   // 8 bf16 = 4 VGPRs
typedef float f32x4  __attribute__((ext_vector_type(4)));
typedef unsigned short us4 __attribute__((ext_vector_type(4)));

#define MFMA(a, b, c) __builtin_amdgcn_mfma_f32_16x16x32_bf16((a), (b), (c), 0, 0, 0)

__device__ inline unsigned short f2bf(float f) {
    unsigned u = __builtin_bit_cast(unsigned, f);
    u = (u + 0x7FFFu + ((u >> 16) & 1u)) >> 16;   // RNE
    return (unsigned short)u;
}

__device__ inline void stage16(const void* g, void* l) {
    __builtin_amdgcn_global_load_lds(
        (const __attribute__((address_space(1))) void*)g,
        (__attribute__((address_space(3))) void*)l,
        16, 0, 0);
}

// ---------------------------------------------------------------------------
// Prep: x f32 -> bf16
// ---------------------------------------------------------------------------
__global__ void conv_x(const float* __restrict__ x, unsigned short* __restrict__ xb) {
    long i = ((long)blockIdx.x * 256 + threadIdx.x) * 4;
    float4 v = *(const float4*)(x + i);
    us4 o = { f2bf(v.x), f2bf(v.y), f2bf(v.z), f2bf(v.w) };
    *(us4*)(xb + i) = o;
}

// ---------------------------------------------------------------------------
// Prep: weight (K=2048 rows x N cols, f32) -> transposed bf16 [N][2048]
// ---------------------------------------------------------------------------
__global__ void transpose_w(const float* __restrict__ in, unsigned short* __restrict__ out,
                            int N, int row_off) {
    __shared__ float t[32][33];
    int tx = threadIdx.x, ty = threadIdx.y;
    int n0 = blockIdx.x * 32, k0 = blockIdx.y * 32;
    for (int i = 0; i < 4; i++)
        t[ty + i * 8][tx] = in[(long)(k0 + ty + i * 8) * N + n0 + tx];
    __syncthreads();
    for (int i = 0; i < 4; i++)
        out[(long)(row_off + n0 + ty + i * 8) * 2048 + k0 + tx] = f2bf(t[tx][ty + i * 8]);
}

// ---------------------------------------------------------------------------
// Prep: V (b,kvh,s,hd) bf16 -> V^T (b,kvh,hd,s) bf16
// ---------------------------------------------------------------------------
__global__ void transpose_v(const unsigned short* __restrict__ v, unsigned short* __restrict__ vt) {
    __shared__ unsigned short t[32][33];
    int tx = threadIdx.x, ty = threadIdx.y;
    int d0 = blockIdx.x * 32, s0 = blockIdx.y * 32, bk = blockIdx.z;
    const unsigned short* vin = v + (long)bk * SEQ * HDIM;
    unsigned short* vo = vt + (long)bk * HDIM * SEQ;
    for (int i = 0; i < 4; i++)
        t[ty + i * 8][tx] = vin[(long)(s0 + ty + i * 8) * HDIM + d0 + tx];
    __syncthreads();
    for (int i = 0; i < 4; i++)
        vo[(long)(d0 + ty + i * 8) * SEQ + s0 + tx] = t[tx][ty + i * 8];
}

// ---------------------------------------------------------------------------
// QKV GEMM (unchanged from R1): C[8192 x 4096] = xb * Wt, RoPE epilogue.
// ---------------------------------------------------------------------------
__launch_bounds__(256, 2)
__global__ void qkv_gemm(const unsigned short* __restrict__ xb,
                         const unsigned short* __restrict__ wt,
                         const float* __restrict__ pcos, const float* __restrict__ psin,
                         unsigned short* __restrict__ qb, unsigned short* __restrict__ kbuf,
                         unsigned short* __restrict__ vbuf) {
    constexpr int K = DIM;
    __shared__ __align__(16) unsigned short As[128 * 32];
    __shared__ __align__(16) unsigned short Bs[128 * 32];
    const int tid = threadIdx.x;
    const int m0 = blockIdx.y * 128;
    const int n0 = blockIdx.x * 128;
    const int w = tid >> 6, lane = tid & 63, qq = lane >> 4, ln = lane & 15;
    const int wm = w >> 1, wn = w & 1;

    f32x4 acc[4][4] = {};

    const int arow = tid >> 2;
    const int acol = (tid & 3) * 8;
    const unsigned short* ag = xb + (long)(m0 + arow) * K + acol;
    const unsigned short* bg = wt + (long)(n0 + arow) * K + acol;
    unsigned short* al = As + tid * 8;
    unsigned short* bl = Bs + tid * 8;

    for (int kk = 0; kk < K; kk += 32) {
        __syncthreads();
        stage16(ag + kk, al);
        stage16(ag + kk + 64 * K, al + 2048);
        stage16(bg + kk, bl);
        stage16(bg + kk + 64 * K, bl + 2048);
        __syncthreads();
        bf16x8 a[4], b[4];
        for (int mt = 0; mt < 4; mt++)
            a[mt] = *(const bf16x8*)&As[(wm * 64 + mt * 16 + ln) * 32 + qq * 8];
        for (int nt = 0; nt < 4; nt++)
            b[nt] = *(const bf16x8*)&Bs[(wn * 64 + nt * 16 + ln) * 32 + qq * 8];
        for (int mt = 0; mt < 4; mt++)
            for (int nt = 0; nt < 4; nt++)
                acc[mt][nt] = MFMA(a[mt], b[nt], acc[mt][nt]);
    }

    for (int mt = 0; mt < 4; mt++) {
        for (int nt = 0; nt < 4; nt++) {
            int n = n0 + wn * 64 + nt * 16 + ln;
            for (int r = 0; r < 4; r++) {
                int m = m0 + wm * 64 + mt * 16 + qq * 4 + r;
                int b_ = m >> 11, s = m & (SEQ - 1);
                float v = acc[mt][nt][r];
                float p = __shfl_xor(v, 1);
                int d = n & (HDIM - 1);
                if (n < 3072) {
                    int i = d >> 1;
                    float c = pcos[s * 64 + i], sn = psin[s * 64 + i];
                    v = (d & 1) ? (p * sn + v * c) : (v * c - p * sn);
                }
                unsigned short bfv = f2bf(v);
                if (n < 2048) {
                    int h = n >> 7;
                    qb[((long)(b_ * NH + h) * SEQ + s) * HDIM + d] = bfv;
                } else if (n < 3072) {
                    int kv = (n - 2048) >> 7;
                    kbuf[((long)(b_ * NKVH + kv) * SEQ + s) * HDIM + d] = bfv;
                } else {
                    int kv = (n - 3072) >> 7;
                    vbuf[((long)(b_ * NKVH + kv) * SEQ + s) * HDIM + d] = bfv;
                }
            }
        }
    }
}

// ---------------------------------------------------------------------------
// Flash attention v2: barrier-free, no LDS for K/V (streamed from global as
// MFMA A-frags), transposed formulation:
//   S^T = K Q^T   (C-layout: row=key, col=q=lane)  -> softmax per-lane column
//   O^T = V^T P^T (A=V^T frag from global, B=P via wave-private LDS [q][key])
// Each wave handles 32 q-rows of Q-tile pair (qt, 15-qt): uniform 17 k-iters.
// Grid 512 blocks x 4 independent waves = 8 waves/CU, all co-resident.
// ---------------------------------------------------------------------------
#define PSTR 140   // P row stride in shorts (280 B): conflict-free b64/b128
__launch_bounds__(256, 2)
__global__ void flash(const unsigned short* __restrict__ qb,
                      const unsigned short* __restrict__ kb,
                      const unsigned short* __restrict__ vtb,
                      unsigned short* __restrict__ aout) {
    __shared__ __align__(16) unsigned short Pls[4][32 * PSTR];
    const int tid = threadIdx.x;
    const int w = tid >> 6, lane = tid & 63, qq = lane >> 4, ln = lane & 15;
    unsigned short* P = Pls[w];

    // block swizzle: XCD = flat%8 (round-robin); pin 4 (b,kv) pairs per XCD
    int f = blockIdx.x + (blockIdx.y << 3) + (blockIdx.z << 7);  // grid (8,16,4)
    int xcd = f & 7, j = f >> 3;
    int bkv = xcd + 8 * (j & 3);          // 0..31
    int b = bkv >> 3, kv = bkv & 7;
    int rem = j >> 2;                     // 0..15
    int h = kv * 2 + (rem & 1);
    int qpair = rem >> 1;                 // 0..7

    const unsigned short* qbase = qb + (long)(b * NH + h) * SEQ * HDIM;
    const unsigned short* kbase = kb + (long)(b * NKVH + kv) * SEQ * HDIM;
    const unsigned short* vbase = vtb + (long)(b * NKVH + kv) * HDIM * SEQ;
    const float scale = 0.088388347648318447f;   // 1/sqrt(128)

    for (int phase = 0; phase < 2; phase++) {
        const int qt = (phase == 0) ? qpair : 15 - qpair;
        const int q0 = qt * 128 + w * 32;          // wave's first q-row

        // Q fragments (B-operand layout: lane=q, k-contiguous)
        bf16x8 qf[2][4];
        for (int nt = 0; nt < 2; nt++)
            for (int ks = 0; ks < 4; ks++)
                qf[nt][ks] = *(const bf16x8*)&qbase[(long)(q0 + nt * 16 + ln) * HDIM + ks * 32 + qq * 8];

        float m[2] = { -3e38f, -3e38f }, l[2] = { 0.f, 0.f };
        f32x4 oacc[8][2] = {};

        #pragma unroll 1
        for (int kt = 0; kt <= qt; kt++) {
            const int k0 = kt * 128;

            // ---- S^T = K Q^T : A = K[key][hd] streamed from global ----
            f32x4 sacc[8][2] = {};
            #pragma unroll
            for (int mt = 0; mt < 8; mt++) {
                const unsigned short* kr = &kbase[(long)(k0 + mt * 16 + ln) * HDIM + qq * 8];
                bf16x8 kf0 = *(const bf16x8*)(kr);
                bf16x8 kf1 = *(const bf16x8*)(kr + 32);
                bf16x8 kf2 = *(const bf16x8*)(kr + 64);
                bf16x8 kf3 = *(const bf16x8*)(kr + 96);
                sacc[mt][0] = MFMA(kf0, qf[0][0], sacc[mt][0]);
                sacc[mt][1] = MFMA(kf0, qf[1][0], sacc[mt][1]);
                sacc[mt][0] = MFMA(kf1, qf[0][1], sacc[mt][0]);
                sacc[mt][1] = MFMA(kf1, qf[1][1], sacc[mt][1]);
                sacc[mt][0] = MFMA(kf2, qf[0][2], sacc[mt][0]);
                sacc[mt][1] = MFMA(kf2, qf[1][2], sacc[mt][1]);
                sacc[mt][0] = MFMA(kf3, qf[0][3], sacc[mt][0]);
                sacc[mt][1] = MFMA(kf3, qf[1][3], sacc[mt][1]);
            }

            // ---- online softmax: lane owns column q = q0 + nt*16 + ln ----
            const bool diag = (kt == qt);
            #pragma unroll
            for (int nt = 0; nt < 2; nt++) {
                const int q = q0 + nt * 16 + ln;
                float mx = m[nt];
                #pragma unroll
                for (int mt = 0; mt < 8; mt++)
                    #pragma unroll
                    for (int r = 0; r < 4; r++) {
                        float v = sacc[mt][nt][r] * scale;
                        if (diag && (k0 + mt * 16 + qq * 4 + r > q)) v = -3e38f;
                        sacc[mt][nt][r] = v;
                        mx = fmaxf(mx, v);
                    }
                mx = fmaxf(mx, __shfl_xor(mx, 16));
                mx = fmaxf(mx, __shfl_xor(mx, 32));
                float alpha = exp2f((m[nt] - mx) * LOG2E);
                m[nt] = mx;
                float rs = 0.f;
                #pragma unroll
                for (int mt = 0; mt < 8; mt++) {
                    float p0 = exp2f((sacc[mt][nt][0] - mx) * LOG2E);
                    float p1 = exp2f((sacc[mt][nt][1] - mx) * LOG2E);
                    float p2 = exp2f((sacc[mt][nt][2] - mx) * LOG2E);
                    float p3 = exp2f((sacc[mt][nt][3] - mx) * LOG2E);
                    rs += (p0 + p1) + (p2 + p3);
                    us4 pu = { f2bf(p0), f2bf(p1), f2bf(p2), f2bf(p3) };
                    *(us4*)&P[(nt * 16 + ln) * PSTR + mt * 16 + qq * 4] = pu;  // [q][key]
                }
                rs += __shfl_xor(rs, 16);
                rs += __shfl_xor(rs, 32);
                l[nt] = l[nt] * alpha + rs;
                #pragma unroll
                for (int mt = 0; mt < 8; mt++)
                    #pragma unroll
                    for (int r = 0; r < 4; r++)
                        oacc[mt][nt][r] *= alpha;
            }

            // ---- O^T += V^T P^T : A = V^T[hd][key] from global, B = P ----
            bf16x8 pf[4][2];
            #pragma unroll
            for (int ks = 0; ks < 4; ks++)
                #pragma unroll
                for (int nt = 0; nt < 2; nt++)
                    pf[ks][nt] = *(const bf16x8*)&P[(nt * 16 + ln) * PSTR + ks * 32 + qq * 8];
            #pragma unroll
            for (int mt = 0; mt < 8; mt++) {
                const unsigned short* vr = &vbase[(long)(mt * 16 + ln) * SEQ + k0 + qq * 8];
                bf16x8 vf0 = *(const bf16x8*)(vr);
                bf16x8 vf1 = *(const bf16x8*)(vr + 32);
                bf16x8 vf2 = *(const bf16x8*)(vr + 64);
                bf16x8 vf3 = *(const bf16x8*)(vr + 96);
                oacc[mt][0] = MFMA(vf0, pf[0][0], oacc[mt][0]);
                oacc[mt][1] = MFMA(vf0, pf[0][1], oacc[mt][1]);
                oacc[mt][0] = MFMA(vf1, pf[1][0], oacc[mt][0]);
                oacc[mt][1] = MFMA(vf1, pf[1][1], oacc[mt][1]);
                oacc[mt][0] = MFMA(vf2, pf[2][0], oacc[mt][0]);
                oacc[mt][1] = MFMA(vf2, pf[2][1], oacc[mt][1]);
                oacc[mt][0] = MFMA(vf3, pf[3][0], oacc[mt][0]);
                oacc[mt][1] = MFMA(vf3, pf[3][1], oacc[mt][1]);
            }
        }

        // ---- epilogue: lane owns column q; d = mt*16 + qq*4 + r ----
        #pragma unroll
        for (int nt = 0; nt < 2; nt++) {
            const int q = q0 + nt * 16 + ln;
            float inv = 1.f / l[nt];
            unsigned short* ao = aout + ((long)b * SEQ + q) * DIM + h * HDIM;
            #pragma unroll
            for (int mt = 0; mt < 8; mt++) {
                us4 o = { f2bf(oacc[mt][nt][0] * inv), f2bf(oacc[mt][nt][1] * inv),
                          f2bf(oacc[mt][nt][2] * inv), f2bf(oacc[mt][nt][3] * inv) };
                *(us4*)&ao[mt * 16 + qq * 4] = o;
            }
        }
    }
}

// ---------------------------------------------------------------------------
// Output GEMM (unchanged): d_out[8192 x 2048] f32 = attn * wo_t
// ---------------------------------------------------------------------------
__launch_bounds__(256, 2)
__global__ void out_gemm(const unsigned short* __restrict__ ab,
                         const unsigned short* __restrict__ wt,
                         float* __restrict__ out) {
    constexpr int K = DIM;
    __shared__ __align__(16) unsigned short As[128 * 32];
    __shared__ __align__(16) unsigned short Bs[128 * 32];
    const int tid = threadIdx.x;
    const int m0 = blockIdx.y * 128;
    const int n0 = blockIdx.x * 128;
    const int w = tid >> 6, lane = tid & 63, qq = lane >> 4, ln = lane & 15;
    const int wm = w >> 1, wn = w & 1;

    f32x4 acc[4][4] = {};

    const int arow = tid >> 2;
    const int acol = (tid & 3) * 8;
    const unsigned short* ag = ab + (long)(m0 + arow) * K + acol;
    const unsigned short* bg = wt + (long)(n0 + arow) * K + acol;
    unsigned short* al = As + tid * 8;
    unsigned short* bl = Bs + tid * 8;

    for (int kk = 0; kk < K; kk += 32) {
        __syncthreads();
        stage16(ag + kk, al);
        stage16(ag + kk + 64 * K, al + 2048);
        stage16(bg + kk, bl);
        stage16(bg + kk + 64 * K, bl + 2048);
        __syncthreads();
        bf16x8 a[4], b[4];
        for (int mt = 0; mt < 4; mt++)
            a[mt] = *(const bf16x8*)&As[(wm * 64 + mt * 16 + ln) * 32 + qq * 8];
        for (int nt = 0; nt < 4; nt++)
            b[nt] = *(const bf16x8*)&Bs[(wn * 64 + nt * 16 + ln) * 32 + qq * 8];
        for (int mt = 0; mt < 4; mt++)
            for (int nt = 0; nt < 4; nt++)
                acc[mt][nt] = MFMA(a[mt], b[nt], acc[mt][nt]);
    }

    for (int mt = 0; mt < 4; mt++)
        for (int nt = 0; nt < 4; nt++) {
            int n = n0 + wn * 64 + nt * 16 + ln;
            for (int r = 0; r < 4; r++) {
                int m = m0 + wm * 64 + mt * 16 + qq * 4 + r;
                out[(long)m * DIM + n] = acc[mt][nt][r];
            }
        }
}

// ---------------------------------------------------------------------------
// Workspace layout: see R1 (unchanged), total 176,160,768 bytes
// ---------------------------------------------------------------------------
extern "C" void kernel_launch(void* const* d_in, const int* in_sizes, int n_in,
                              void* d_out, int out_size, void* d_ws, size_t ws_size,
                              hipStream_t stream) {
    const float* x    = (const float*)d_in[0];
    const float* wq   = (const float*)d_in[1];
    const float* wk   = (const float*)d_in[2];
    const float* wv   = (const float*)d_in[3];
    const float* wo   = (const float*)d_in[4];
    const float* pcos = (const float*)d_in[5];
    const float* psin = (const float*)d_in[6];
    float* out = (float*)d_out;

    char* ws = (char*)d_ws;
    unsigned short* xb    = (unsigned short*)(ws);
    unsigned short* wqkvt = (unsigned short*)(ws + 33554432L);
    unsigned short* wot   = (unsigned short*)(ws + 50331648L);
    unsigned short* qbuf  = (unsigned short*)(ws + 58720256L);
    unsigned short* kbuf  = (unsigned short*)(ws + 92274688L);
    unsigned short* vbuf  = (unsigned short*)(ws + 109051904L);
    unsigned short* vtb   = (unsigned short*)(ws + 125829120L);
    unsigned short* aout  = (unsigned short*)(ws + 142606336L);

    conv_x<<<16384, 256, 0, stream>>>(x, xb);
    transpose_w<<<dim3(64, 64), dim3(32, 8), 0, stream>>>(wq, wqkvt, 2048, 0);
    transpose_w<<<dim3(32, 64), dim3(32, 8), 0, stream>>>(wk, wqkvt, 1024, 2048);
    transpose_w<<<dim3(32, 64), dim3(32, 8), 0, stream>>>(wv, wqkvt, 1024, 3072);
    transpose_w<<<dim3(64, 64), dim3(32, 8), 0, stream>>>(wo, wot, 2048, 0);

    qkv_gemm<<<dim3(32, 64), 256, 0, stream>>>(xb, wqkvt, pcos, psin, qbuf, kbuf, vbuf);
    transpose_v<<<dim3(4, 64, 32), dim3(32, 8), 0, stream>>>(vbuf, vtb);
    flash<<<dim3(8, 16, 4), 256, 0, stream>>>(qbuf, kbuf, vtb, aout);
    out_gemm<<<dim3(16, 64), 256, 0, stream>>>(aout, wot, out);
}

// Round 4
// 573.706 us; speedup vs baseline: 1.5837x; 1.2114x over previous
//
#include <hip/hip_runtime.h>
#include <stdint.h>

// ---------------------------------------------------------------------------
// Problem constants: B=4, S=2048, D=2048, H=16, KVH=8, HD=128, N_REP=2
// ---------------------------------------------------------------------------
#define SEQ   2048
#define DIM   2048
#define NH    16
#define NKVH  8
#define HDIM  128
#define MTOT  8192      // B*S
#define LOG2E 1.44269504088896340736f

typedef short bf16x8 __attribute__((ext_vector_type(8)));   // 8 bf16 = 4 VGPRs
typedef float f32x4  __attribute__((ext_vector_type(4)));
typedef unsigned short us4 __attribute__((ext_vector_type(4)));

#define MFMA(a, b, c) __builtin_amdgcn_mfma_f32_16x16x32_bf16((a), (b), (c), 0, 0, 0)

__device__ inline unsigned short f2bf(float f) {
    unsigned u = __builtin_bit_cast(unsigned, f);
    u = (u + 0x7FFFu + ((u >> 16) & 1u)) >> 16;   // RNE
    return (unsigned short)u;
}

__device__ inline void stage16(const void* g, void* l) {
    __builtin_amdgcn_global_load_lds(
        (const __attribute__((address_space(1))) void*)g,
        (__attribute__((address_space(3))) void*)l,
        16, 0, 0);
}

// ---------------------------------------------------------------------------
// Prep: x f32 -> bf16
// ---------------------------------------------------------------------------
__global__ void conv_x(const float* __restrict__ x, unsigned short* __restrict__ xb) {
    long i = ((long)blockIdx.x * 256 + threadIdx.x) * 4;
    float4 v = *(const float4*)(x + i);
    us4 o = { f2bf(v.x), f2bf(v.y), f2bf(v.z), f2bf(v.w) };
    *(us4*)(xb + i) = o;
}

// ---------------------------------------------------------------------------
// Prep: weight (K=2048 rows x N cols, f32) -> transposed bf16 [N][2048]
// ---------------------------------------------------------------------------
__global__ void transpose_w(const float* __restrict__ in, unsigned short* __restrict__ out,
                            int N, int row_off) {
    __shared__ float t[32][33];
    int tx = threadIdx.x, ty = threadIdx.y;
    int n0 = blockIdx.x * 32, k0 = blockIdx.y * 32;
    for (int i = 0; i < 4; i++)
        t[ty + i * 8][tx] = in[(long)(k0 + ty + i * 8) * N + n0 + tx];
    __syncthreads();
    for (int i = 0; i < 4; i++)
        out[(long)(row_off + n0 + ty + i * 8) * 2048 + k0 + tx] = f2bf(t[tx][ty + i * 8]);
}

// ---------------------------------------------------------------------------
// Prep: V (b,kvh,s,hd) bf16 -> V^T (b,kvh,hd,s) bf16
// ---------------------------------------------------------------------------
__global__ void transpose_v(const unsigned short* __restrict__ v, unsigned short* __restrict__ vt) {
    __shared__ unsigned short t[32][33];
    int tx = threadIdx.x, ty = threadIdx.y;
    int d0 = blockIdx.x * 32, s0 = blockIdx.y * 32, bk = blockIdx.z;
    const unsigned short* vin = v + (long)bk * SEQ * HDIM;
    unsigned short* vo = vt + (long)bk * HDIM * SEQ;
    for (int i = 0; i < 4; i++)
        t[ty + i * 8][tx] = vin[(long)(s0 + ty + i * 8) * HDIM + d0 + tx];
    __syncthreads();
    for (int i = 0; i < 4; i++)
        vo[(long)(d0 + ty + i * 8) * SEQ + s0 + tx] = t[tx][ty + i * 8];
}

// ---------------------------------------------------------------------------
// QKV GEMM (unchanged): C[8192 x 4096] = xb * Wt, RoPE epilogue.
// ---------------------------------------------------------------------------
__launch_bounds__(256, 2)
__global__ void qkv_gemm(const unsigned short* __restrict__ xb,
                         const unsigned short* __restrict__ wt,
                         const float* __restrict__ pcos, const float* __restrict__ psin,
                         unsigned short* __restrict__ qb, unsigned short* __restrict__ kbuf,
                         unsigned short* __restrict__ vbuf) {
    constexpr int K = DIM;
    __shared__ __align__(16) unsigned short As[128 * 32];
    __shared__ __align__(16) unsigned short Bs[128 * 32];
    const int tid = threadIdx.x;
    const int m0 = blockIdx.y * 128;
    const int n0 = blockIdx.x * 128;
    const int w = tid >> 6, lane = tid & 63, qq = lane >> 4, ln = lane & 15;
    const int wm = w >> 1, wn = w & 1;

    f32x4 acc[4][4] = {};

    const int arow = tid >> 2;
    const int acol = (tid & 3) * 8;
    const unsigned short* ag = xb + (long)(m0 + arow) * K + acol;
    const unsigned short* bg = wt + (long)(n0 + arow) * K + acol;
    unsigned short* al = As + tid * 8;
    unsigned short* bl = Bs + tid * 8;

    for (int kk = 0; kk < K; kk += 32) {
        __syncthreads();
        stage16(ag + kk, al);
        stage16(ag + kk + 64 * K, al + 2048);
        stage16(bg + kk, bl);
        stage16(bg + kk + 64 * K, bl + 2048);
        __syncthreads();
        bf16x8 a[4], b[4];
        for (int mt = 0; mt < 4; mt++)
            a[mt] = *(const bf16x8*)&As[(wm * 64 + mt * 16 + ln) * 32 + qq * 8];
        for (int nt = 0; nt < 4; nt++)
            b[nt] = *(const bf16x8*)&Bs[(wn * 64 + nt * 16 + ln) * 32 + qq * 8];
        for (int mt = 0; mt < 4; mt++)
            for (int nt = 0; nt < 4; nt++)
                acc[mt][nt] = MFMA(a[mt], b[nt], acc[mt][nt]);
    }

    for (int mt = 0; mt < 4; mt++) {
        for (int nt = 0; nt < 4; nt++) {
            int n = n0 + wn * 64 + nt * 16 + ln;
            for (int r = 0; r < 4; r++) {
                int m = m0 + wm * 64 + mt * 16 + qq * 4 + r;
                int b_ = m >> 11, s = m & (SEQ - 1);
                float v = acc[mt][nt][r];
                float p = __shfl_xor(v, 1);
                int d = n & (HDIM - 1);
                if (n < 3072) {
                    int i = d >> 1;
                    float c = pcos[s * 64 + i], sn = psin[s * 64 + i];
                    v = (d & 1) ? (p * sn + v * c) : (v * c - p * sn);
                }
                unsigned short bfv = f2bf(v);
                if (n < 2048) {
                    int h = n >> 7;
                    qb[((long)(b_ * NH + h) * SEQ + s) * HDIM + d] = bfv;
                } else if (n < 3072) {
                    int kv = (n - 2048) >> 7;
                    kbuf[((long)(b_ * NKVH + kv) * SEQ + s) * HDIM + d] = bfv;
                } else {
                    int kv = (n - 3072) >> 7;
                    vbuf[((long)(b_ * NKVH + kv) * SEQ + s) * HDIM + d] = bfv;
                }
            }
        }
    }
}

// ---------------------------------------------------------------------------
// Flash attention v3b: identical to v3 except the V^T staging LDS offset is
// fixed (bytes 32768, was 65536 = past end of the 64 KB block -> NaN).
// K/V staged via bulk async global_load_lds, XOR-swizzled layout, transposed
// math (S^T = K Q^T, O^T = V^T P^T), P overlays K region per-wave.
// ---------------------------------------------------------------------------
__launch_bounds__(256, 2)
__global__ void flash(const unsigned short* __restrict__ qb,
                      const unsigned short* __restrict__ kb,
                      const unsigned short* __restrict__ vtb,
                      unsigned short* __restrict__ aout) {
    __shared__ __align__(16) unsigned short KV[32768];   // K: shorts [0,16384)  V^T: [16384,32768)
    const int tid = threadIdx.x;
    const int w = tid >> 6, lane = tid & 63, qq = lane >> 4, ln = lane & 15;
    unsigned short* Pseg = KV + w * 4096;                // P overlay, wave-private 8 KB

    // block swizzle: XCD = flat%8; pin 4 (b,kv) pairs per XCD
    int f = blockIdx.x + (blockIdx.y << 3) + (blockIdx.z << 7);  // grid (8,16,4)
    int xcd = f & 7, j = f >> 3;
    int bkv = xcd + 8 * (j & 3);
    int b = bkv >> 3, kv = bkv & 7;
    int rem = j >> 2;
    int h = kv * 2 + (rem & 1);
    int qpair = rem >> 1;

    const unsigned short* qbase = qb + (long)(b * NH + h) * SEQ * HDIM;
    const unsigned short* kbase = kb + (long)(b * NKVH + kv) * SEQ * HDIM;
    const unsigned short* vbase = vtb + (long)(b * NKVH + kv) * HDIM * SEQ;
    const float SCL2 = 0.088388347648318447f * LOG2E;   // scale * log2(e), folded

    const int srow = tid >> 4;                 // staging: row within 16-row group
    const int sswz = (tid & 15) ^ srow;        // staging: swizzled source unit

    for (int phase = 0; phase < 2; phase++) {
        const int qt = (phase == 0) ? qpair : 15 - qpair;
        const int q0 = qt * 128 + w * 32;

        // Q fragments (B-operand layout: lane=q, k-contiguous)
        bf16x8 qf[2][4];
        for (int nt = 0; nt < 2; nt++)
            for (int ks = 0; ks < 4; ks++)
                qf[nt][ks] = *(const bf16x8*)&qbase[(long)(q0 + nt * 16 + ln) * HDIM + ks * 32 + qq * 8];

        float m[2] = { -3e38f, -3e38f }, l[2] = { 0.f, 0.f };
        f32x4 oacc[8][2] = {};

        #pragma unroll 1
        for (int kt = 0; kt <= qt; kt++) {
            const int k0 = kt * 128;

            __syncthreads();   // B_pre: everyone done reading previous K/V/P
            // stage K [key][hd-unit^swz] and V^T [hd][key-unit^swz]
            char* kl = (char*)KV;
            #pragma unroll
            for (int r = 0; r < 8; r++) {
                int key = r * 16 + srow;
                stage16(kbase + (long)(k0 + key) * HDIM + sswz * 8, kl + r * 4096 + tid * 16);
            }
            #pragma unroll
            for (int r = 0; r < 8; r++) {
                int hd = r * 16 + srow;
                stage16(vbase + (long)hd * SEQ + k0 + sswz * 8, kl + 32768 + r * 4096 + tid * 16);
            }
            __syncthreads();   // B_vis: compiler's vmcnt(0) drain + visibility

            // ---- S^T = K Q^T : A-frags from swizzled LDS ----
            f32x4 sacc[8][2] = {};
            #pragma unroll
            for (int mt = 0; mt < 8; mt++) {
                const unsigned short* kr = &KV[(mt * 16 + ln) * 128];
                bf16x8 kf0 = *(const bf16x8*)&kr[((0 + qq) ^ ln) * 8];
                bf16x8 kf1 = *(const bf16x8*)&kr[((4 + qq) ^ ln) * 8];
                bf16x8 kf2 = *(const bf16x8*)&kr[((8 + qq) ^ ln) * 8];
                bf16x8 kf3 = *(const bf16x8*)&kr[((12 + qq) ^ ln) * 8];
                sacc[mt][0] = MFMA(kf0, qf[0][0], sacc[mt][0]);
                sacc[mt][1] = MFMA(kf0, qf[1][0], sacc[mt][1]);
                sacc[mt][0] = MFMA(kf1, qf[0][1], sacc[mt][0]);
                sacc[mt][1] = MFMA(kf1, qf[1][1], sacc[mt][1]);
                sacc[mt][0] = MFMA(kf2, qf[0][2], sacc[mt][0]);
                sacc[mt][1] = MFMA(kf2, qf[1][2], sacc[mt][1]);
                sacc[mt][0] = MFMA(kf3, qf[0][3], sacc[mt][0]);
                sacc[mt][1] = MFMA(kf3, qf[1][3], sacc[mt][1]);
            }

            __syncthreads();   // B_k: all waves done reading K region (P overlays it)

            // ---- online softmax in raw units (scale folded into SCL2) ----
            const bool diag = (kt == qt);
            #pragma unroll
            for (int nt = 0; nt < 2; nt++) {
                const int q = q0 + nt * 16 + ln;
                float mx = m[nt];
                #pragma unroll
                for (int mt = 0; mt < 8; mt++)
                    #pragma unroll
                    for (int r = 0; r < 4; r++) {
                        float v = sacc[mt][nt][r];
                        if (diag && (k0 + mt * 16 + qq * 4 + r > q)) v = -3e38f;
                        sacc[mt][nt][r] = v;
                        mx = fmaxf(mx, v);
                    }
                mx = fmaxf(mx, __shfl_xor(mx, 16));
                mx = fmaxf(mx, __shfl_xor(mx, 32));
                float alpha = exp2f((m[nt] - mx) * SCL2);
                m[nt] = mx;
                float rs = 0.f;
                #pragma unroll
                for (int mt = 0; mt < 8; mt++) {
                    float p0 = exp2f((sacc[mt][nt][0] - mx) * SCL2);
                    float p1 = exp2f((sacc[mt][nt][1] - mx) * SCL2);
                    float p2 = exp2f((sacc[mt][nt][2] - mx) * SCL2);
                    float p3 = exp2f((sacc[mt][nt][3] - mx) * SCL2);
                    rs += (p0 + p1) + (p2 + p3);
                    us4 pu = { f2bf(p0), f2bf(p1), f2bf(p2), f2bf(p3) };
                    // P[q][key]: row q=nt*16+ln, key-unit mt*2+(qq>>1), swizzle ^ln
                    *(us4*)&Pseg[(nt * 16 + ln) * 128 + ((mt * 2 + (qq >> 1)) ^ ln) * 8 + (qq & 1) * 4] = pu;
                }
                rs += __shfl_xor(rs, 16);
                rs += __shfl_xor(rs, 32);
                l[nt] = l[nt] * alpha + rs;
                #pragma unroll
                for (int mt = 0; mt < 8; mt++)
                    #pragma unroll
                    for (int r = 0; r < 4; r++)
                        oacc[mt][nt][r] *= alpha;
            }

            // ---- O^T += V^T P^T : A = V^T frags, B = P frags (both LDS) ----
            bf16x8 pf[4][2];
            #pragma unroll
            for (int ks = 0; ks < 4; ks++)
                #pragma unroll
                for (int nt = 0; nt < 2; nt++)
                    pf[ks][nt] = *(const bf16x8*)&Pseg[(nt * 16 + ln) * 128 + ((ks * 4 + qq) ^ ln) * 8];
            #pragma unroll
            for (int mt = 0; mt < 8; mt++) {
                const unsigned short* vr = &KV[16384 + (mt * 16 + ln) * 128];
                bf16x8 vf0 = *(const bf16x8*)&vr[((0 + qq) ^ ln) * 8];
                bf16x8 vf1 = *(const bf16x8*)&vr[((4 + qq) ^ ln) * 8];
                bf16x8 vf2 = *(const bf16x8*)&vr[((8 + qq) ^ ln) * 8];
                bf16x8 vf3 = *(const bf16x8*)&vr[((12 + qq) ^ ln) * 8];
                oacc[mt][0] = MFMA(vf0, pf[0][0], oacc[mt][0]);
                oacc[mt][1] = MFMA(vf0, pf[0][1], oacc[mt][1]);
                oacc[mt][0] = MFMA(vf1, pf[1][0], oacc[mt][0]);
                oacc[mt][1] = MFMA(vf1, pf[1][1], oacc[mt][1]);
                oacc[mt][0] = MFMA(vf2, pf[2][0], oacc[mt][0]);
                oacc[mt][1] = MFMA(vf2, pf[2][1], oacc[mt][1]);
                oacc[mt][0] = MFMA(vf3, pf[3][0], oacc[mt][0]);
                oacc[mt][1] = MFMA(vf3, pf[3][1], oacc[mt][1]);
            }
        }

        // ---- epilogue: lane owns column q; d = mt*16 + qq*4 + r ----
        #pragma unroll
        for (int nt = 0; nt < 2; nt++) {
            const int q = q0 + nt * 16 + ln;
            float inv = 1.f / l[nt];
            unsigned short* ao = aout + ((long)b * SEQ + q) * DIM + h * HDIM;
            #pragma unroll
            for (int mt = 0; mt < 8; mt++) {
                us4 o = { f2bf(oacc[mt][nt][0] * inv), f2bf(oacc[mt][nt][1] * inv),
                          f2bf(oacc[mt][nt][2] * inv), f2bf(oacc[mt][nt][3] * inv) };
                *(us4*)&ao[mt * 16 + qq * 4] = o;
            }
        }
    }
}

// ---------------------------------------------------------------------------
// Output GEMM (unchanged): d_out[8192 x 2048] f32 = attn * wo_t
// ---------------------------------------------------------------------------
__launch_bounds__(256, 2)
__global__ void out_gemm(const unsigned short* __restrict__ ab,
                         const unsigned short* __restrict__ wt,
                         float* __restrict__ out) {
    constexpr int K = DIM;
    __shared__ __align__(16) unsigned short As[128 * 32];
    __shared__ __align__(16) unsigned short Bs[128 * 32];
    const int tid = threadIdx.x;
    const int m0 = blockIdx.y * 128;
    const int n0 = blockIdx.x * 128;
    const int w = tid >> 6, lane = tid & 63, qq = lane >> 4, ln = lane & 15;
    const int wm = w >> 1, wn = w & 1;

    f32x4 acc[4][4] = {};

    const int arow = tid >> 2;
    const int acol = (tid & 3) * 8;
    const unsigned short* ag = ab + (long)(m0 + arow) * K + acol;
    const unsigned short* bg = wt + (long)(n0 + arow) * K + acol;
    unsigned short* al = As + tid * 8;
    unsigned short* bl = Bs + tid * 8;

    for (int kk = 0; kk < K; kk += 32) {
        __syncthreads();
        stage16(ag + kk, al);
        stage16(ag + kk + 64 * K, al + 2048);
        stage16(bg + kk, bl);
        stage16(bg + kk + 64 * K, bl + 2048);
        __syncthreads();
        bf16x8 a[4], b[4];
        for (int mt = 0; mt < 4; mt++)
            a[mt] = *(const bf16x8*)&As[(wm * 64 + mt * 16 + ln) * 32 + qq * 8];
        for (int nt = 0; nt < 4; nt++)
            b[nt] = *(const bf16x8*)&Bs[(wn * 64 + nt * 16 + ln) * 32 + qq * 8];
        for (int mt = 0; mt < 4; mt++)
            for (int nt = 0; nt < 4; nt++)
                acc[mt][nt] = MFMA(a[mt], b[nt], acc[mt][nt]);
    }

    for (int mt = 0; mt < 4; mt++)
        for (int nt = 0; nt < 4; nt++) {
            int n = n0 + wn * 64 + nt * 16 + ln;
            for (int r = 0; r < 4; r++) {
                int m = m0 + wm * 64 + mt * 16 + qq * 4 + r;
                out[(long)m * DIM + n] = acc[mt][nt][r];
            }
        }
}

// ---------------------------------------------------------------------------
// Workspace layout: see R1 (unchanged), total 176,160,768 bytes
// ---------------------------------------------------------------------------
extern "C" void kernel_launch(void* const* d_in, const int* in_sizes, int n_in,
                              void* d_out, int out_size, void* d_ws, size_t ws_size,
                              hipStream_t stream) {
    const float* x    = (const float*)d_in[0];
    const float* wq   = (const float*)d_in[1];
    const float* wk   = (const float*)d_in[2];
    const float* wv   = (const float*)d_in[3];
    const float* wo   = (const float*)d_in[4];
    const float* pcos = (const float*)d_in[5];
    const float* psin = (const float*)d_in[6];
    float* out = (float*)d_out;

    char* ws = (char*)d_ws;
    unsigned short* xb    = (unsigned short*)(ws);
    unsigned short* wqkvt = (unsigned short*)(ws + 33554432L);
    unsigned short* wot   = (unsigned short*)(ws + 50331648L);
    unsigned short* qbuf  = (unsigned short*)(ws + 58720256L);
    unsigned short* kbuf  = (unsigned short*)(ws + 92274688L);
    unsigned short* vbuf  = (unsigned short*)(ws + 109051904L);
    unsigned short* vtb   = (unsigned short*)(ws + 125829120L);
    unsigned short* aout  = (unsigned short*)(ws + 142606336L);

    conv_x<<<16384, 256, 0, stream>>>(x, xb);
    transpose_w<<<dim3(64, 64), dim3(32, 8), 0, stream>>>(wq, wqkvt, 2048, 0);
    transpose_w<<<dim3(32, 64), dim3(32, 8), 0, stream>>>(wk, wqkvt, 1024, 2048);
    transpose_w<<<dim3(32, 64), dim3(32, 8), 0, stream>>>(wv, wqkvt, 1024, 3072);
    transpose_w<<<dim3(64, 64), dim3(32, 8), 0, stream>>>(wo, wot, 2048, 0);

    qkv_gemm<<<dim3(32, 64), 256, 0, stream>>>(xb, wqkvt, pcos, psin, qbuf, kbuf, vbuf);
    transpose_v<<<dim3(4, 64, 32), dim3(32, 8), 0, stream>>>(vbuf, vtb);
    flash<<<dim3(8, 16, 4), 256, 0, stream>>>(qbuf, kbuf, vtb, aout);
    out_gemm<<<dim3(16, 64), 256, 0, stream>>>(aout, wot, out);
}

// Round 5
// 559.641 us; speedup vs baseline: 1.6235x; 1.0251x over previous
//
#include <hip/hip_runtime.h>
#include <stdint.h>

// ---------------------------------------------------------------------------
// Problem constants: B=4, S=2048, D=2048, H=16, KVH=8, HD=128, N_REP=2
// ---------------------------------------------------------------------------
#define SEQ   2048
#define DIM   2048
#define NH    16
#define NKVH  8
#define HDIM  128
#define MTOT  8192      // B*S
#define LOG2E 1.44269504088896340736f

typedef short bf16x8 __attribute__((ext_vector_type(8)));   // 8 bf16 = 4 VGPRs
typedef float f32x4  __attribute__((ext_vector_type(4)));
typedef unsigned short us4 __attribute__((ext_vector_type(4)));

#define MFMA(a, b, c) __builtin_amdgcn_mfma_f32_16x16x32_bf16((a), (b), (c), 0, 0, 0)

__device__ inline unsigned short f2bf(float f) {
    unsigned u = __builtin_bit_cast(unsigned, f);
    u = (u + 0x7FFFu + ((u >> 16) & 1u)) >> 16;   // RNE
    return (unsigned short)u;
}

__device__ inline void stage16(const void* g, void* l) {
    __builtin_amdgcn_global_load_lds(
        (const __attribute__((address_space(1))) void*)g,
        (__attribute__((address_space(3))) void*)l,
        16, 0, 0);
}

// ---------------------------------------------------------------------------
// Prep: x f32 -> bf16
// ---------------------------------------------------------------------------
__global__ void conv_x(const float* __restrict__ x, unsigned short* __restrict__ xb) {
    long i = ((long)blockIdx.x * 256 + threadIdx.x) * 4;
    float4 v = *(const float4*)(x + i);
    us4 o = { f2bf(v.x), f2bf(v.y), f2bf(v.z), f2bf(v.w) };
    *(us4*)(xb + i) = o;
}

// ---------------------------------------------------------------------------
// Prep: weight (K=2048 rows x N cols, f32) -> transposed bf16 [N][2048]
// ---------------------------------------------------------------------------
__global__ void transpose_w(const float* __restrict__ in, unsigned short* __restrict__ out,
                            int N, int row_off) {
    __shared__ float t[32][33];
    int tx = threadIdx.x, ty = threadIdx.y;
    int n0 = blockIdx.x * 32, k0 = blockIdx.y * 32;
    for (int i = 0; i < 4; i++)
        t[ty + i * 8][tx] = in[(long)(k0 + ty + i * 8) * N + n0 + tx];
    __syncthreads();
    for (int i = 0; i < 4; i++)
        out[(long)(row_off + n0 + ty + i * 8) * 2048 + k0 + tx] = f2bf(t[tx][ty + i * 8]);
}

// ---------------------------------------------------------------------------
// Prep: V (b,kvh,s,hd) bf16 -> V^T (b,kvh,hd,s) bf16
// ---------------------------------------------------------------------------
__global__ void transpose_v(const unsigned short* __restrict__ v, unsigned short* __restrict__ vt) {
    __shared__ unsigned short t[32][33];
    int tx = threadIdx.x, ty = threadIdx.y;
    int d0 = blockIdx.x * 32, s0 = blockIdx.y * 32, bk = blockIdx.z;
    const unsigned short* vin = v + (long)bk * SEQ * HDIM;
    unsigned short* vo = vt + (long)bk * HDIM * SEQ;
    for (int i = 0; i < 4; i++)
        t[ty + i * 8][tx] = vin[(long)(s0 + ty + i * 8) * HDIM + d0 + tx];
    __syncthreads();
    for (int i = 0; i < 4; i++)
        vo[(long)(d0 + ty + i * 8) * SEQ + s0 + tx] = t[tx][ty + i * 8];
}

// ---------------------------------------------------------------------------
// QKV GEMM v2: C^T formulation — MFMA(b, a, .) puts n in the register dim
// (4 consecutive d per lane) and m=(b,s) in the lane dim.  RoPE is in-lane
// (no shuffles), stores are aligned us4 (8 B), q/k/v + RoPE branches are
// block-uniform.  Staging/LDS identical to R4.
// ---------------------------------------------------------------------------
__launch_bounds__(256, 2)
__global__ void qkv_gemm(const unsigned short* __restrict__ xb,
                         const unsigned short* __restrict__ wt,
                         const float* __restrict__ pcos, const float* __restrict__ psin,
                         unsigned short* __restrict__ qb, unsigned short* __restrict__ kbuf,
                         unsigned short* __restrict__ vbuf) {
    constexpr int K = DIM;
    __shared__ __align__(16) unsigned short As[128 * 32];
    __shared__ __align__(16) unsigned short Bs[128 * 32];
    const int tid = threadIdx.x;
    const int m0 = blockIdx.y * 128;
    const int n0 = blockIdx.x * 128;
    const int w = tid >> 6, lane = tid & 63, qq = lane >> 4, ln = lane & 15;
    const int wm = w >> 1, wn = w & 1;

    f32x4 acc[4][4] = {};

    const int arow = tid >> 2;
    const int acol = (tid & 3) * 8;
    const unsigned short* ag = xb + (long)(m0 + arow) * K + acol;
    const unsigned short* bg = wt + (long)(n0 + arow) * K + acol;
    unsigned short* al = As + tid * 8;
    unsigned short* bl = Bs + tid * 8;

    for (int kk = 0; kk < K; kk += 32) {
        __syncthreads();
        stage16(ag + kk, al);
        stage16(ag + kk + 64 * K, al + 2048);
        stage16(bg + kk, bl);
        stage16(bg + kk + 64 * K, bl + 2048);
        __syncthreads();
        bf16x8 a[4], b[4];
        for (int mt = 0; mt < 4; mt++)
            a[mt] = *(const bf16x8*)&As[(wm * 64 + mt * 16 + ln) * 32 + qq * 8];
        for (int nt = 0; nt < 4; nt++)
            b[nt] = *(const bf16x8*)&Bs[(wn * 64 + nt * 16 + ln) * 32 + qq * 8];
        for (int mt = 0; mt < 4; mt++)
            for (int nt = 0; nt < 4; nt++)
                acc[mt][nt] = MFMA(b[nt], a[mt], acc[mt][nt]);   // C^T: rows=n, cols=m
    }

    // epilogue: n = n0 + wn*64 + nt*16 + qq*4 + r (regs), m = m0 + wm*64 + mt*16 + ln
    const bool isv = (n0 >= 3072);          // block-uniform: no RoPE for v
    for (int mt = 0; mt < 4; mt++) {
        int m = m0 + wm * 64 + mt * 16 + ln;
        int b_ = m >> 11, s = m & (SEQ - 1);
        const float* crow = pcos + s * 64;
        const float* srow = psin + s * 64;
        for (int nt = 0; nt < 4; nt++) {
            int n = n0 + wn * 64 + nt * 16 + qq * 4;
            int d = n & (HDIM - 1);
            f32x4 v = acc[mt][nt];
            float o0, o1, o2, o3;
            if (!isv) {                      // RoPE, pairs in-lane: (d,d+1),(d+2,d+3)
                int i = d >> 1;
                float2 cc = *(const float2*)(crow + i);
                float2 ss = *(const float2*)(srow + i);
                o0 = v[0] * cc.x - v[1] * ss.x;
                o1 = v[0] * ss.x + v[1] * cc.x;
                o2 = v[2] * cc.y - v[3] * ss.y;
                o3 = v[2] * ss.y + v[3] * cc.y;
            } else {
                o0 = v[0]; o1 = v[1]; o2 = v[2]; o3 = v[3];
            }
            us4 pu = { f2bf(o0), f2bf(o1), f2bf(o2), f2bf(o3) };
            if (n < 2048) {
                int hh = n >> 7;
                *(us4*)&qb[((long)(b_ * NH + hh) * SEQ + s) * HDIM + d] = pu;
            } else if (n < 3072) {
                int kvh = (n - 2048) >> 7;
                *(us4*)&kbuf[((long)(b_ * NKVH + kvh) * SEQ + s) * HDIM + d] = pu;
            } else {
                int kvh = (n - 3072) >> 7;
                *(us4*)&vbuf[((long)(b_ * NKVH + kvh) * SEQ + s) * HDIM + d] = pu;
            }
        }
    }
}

// ---------------------------------------------------------------------------
// Flash attention v3b (unchanged from R4): bulk async K/V staging, XOR
// swizzle, transposed math, P overlays K region per-wave.
// ---------------------------------------------------------------------------
__launch_bounds__(256, 2)
__global__ void flash(const unsigned short* __restrict__ qb,
                      const unsigned short* __restrict__ kb,
                      const unsigned short* __restrict__ vtb,
                      unsigned short* __restrict__ aout) {
    __shared__ __align__(16) unsigned short KV[32768];   // K: shorts [0,16384)  V^T: [16384,32768)
    const int tid = threadIdx.x;
    const int w = tid >> 6, lane = tid & 63, qq = lane >> 4, ln = lane & 15;
    unsigned short* Pseg = KV + w * 4096;                // P overlay, wave-private 8 KB

    // block swizzle: XCD = flat%8; pin 4 (b,kv) pairs per XCD
    int f = blockIdx.x + (blockIdx.y << 3) + (blockIdx.z << 7);  // grid (8,16,4)
    int xcd = f & 7, j = f >> 3;
    int bkv = xcd + 8 * (j & 3);
    int b = bkv >> 3, kv = bkv & 7;
    int rem = j >> 2;
    int h = kv * 2 + (rem & 1);
    int qpair = rem >> 1;

    const unsigned short* qbase = qb + (long)(b * NH + h) * SEQ * HDIM;
    const unsigned short* kbase = kb + (long)(b * NKVH + kv) * SEQ * HDIM;
    const unsigned short* vbase = vtb + (long)(b * NKVH + kv) * HDIM * SEQ;
    const float SCL2 = 0.088388347648318447f * LOG2E;   // scale * log2(e), folded

    const int srow = tid >> 4;                 // staging: row within 16-row group
    const int sswz = (tid & 15) ^ srow;        // staging: swizzled source unit

    for (int phase = 0; phase < 2; phase++) {
        const int qt = (phase == 0) ? qpair : 15 - qpair;
        const int q0 = qt * 128 + w * 32;

        // Q fragments (B-operand layout: lane=q, k-contiguous)
        bf16x8 qf[2][4];
        for (int nt = 0; nt < 2; nt++)
            for (int ks = 0; ks < 4; ks++)
                qf[nt][ks] = *(const bf16x8*)&qbase[(long)(q0 + nt * 16 + ln) * HDIM + ks * 32 + qq * 8];

        float m[2] = { -3e38f, -3e38f }, l[2] = { 0.f, 0.f };
        f32x4 oacc[8][2] = {};

        #pragma unroll 1
        for (int kt = 0; kt <= qt; kt++) {
            const int k0 = kt * 128;

            __syncthreads();   // B_pre: everyone done reading previous K/V/P
            // stage K [key][hd-unit^swz] and V^T [hd][key-unit^swz]
            char* kl = (char*)KV;
            #pragma unroll
            for (int r = 0; r < 8; r++) {
                int key = r * 16 + srow;
                stage16(kbase + (long)(k0 + key) * HDIM + sswz * 8, kl + r * 4096 + tid * 16);
            }
            #pragma unroll
            for (int r = 0; r < 8; r++) {
                int hd = r * 16 + srow;
                stage16(vbase + (long)hd * SEQ + k0 + sswz * 8, kl + 32768 + r * 4096 + tid * 16);
            }
            __syncthreads();   // B_vis: compiler's vmcnt(0) drain + visibility

            // ---- S^T = K Q^T : A-frags from swizzled LDS ----
            f32x4 sacc[8][2] = {};
            #pragma unroll
            for (int mt = 0; mt < 8; mt++) {
                const unsigned short* kr = &KV[(mt * 16 + ln) * 128];
                bf16x8 kf0 = *(const bf16x8*)&kr[((0 + qq) ^ ln) * 8];
                bf16x8 kf1 = *(const bf16x8*)&kr[((4 + qq) ^ ln) * 8];
                bf16x8 kf2 = *(const bf16x8*)&kr[((8 + qq) ^ ln) * 8];
                bf16x8 kf3 = *(const bf16x8*)&kr[((12 + qq) ^ ln) * 8];
                sacc[mt][0] = MFMA(kf0, qf[0][0], sacc[mt][0]);
                sacc[mt][1] = MFMA(kf0, qf[1][0], sacc[mt][1]);
                sacc[mt][0] = MFMA(kf1, qf[0][1], sacc[mt][0]);
                sacc[mt][1] = MFMA(kf1, qf[1][1], sacc[mt][1]);
                sacc[mt][0] = MFMA(kf2, qf[0][2], sacc[mt][0]);
                sacc[mt][1] = MFMA(kf2, qf[1][2], sacc[mt][1]);
                sacc[mt][0] = MFMA(kf3, qf[0][3], sacc[mt][0]);
                sacc[mt][1] = MFMA(kf3, qf[1][3], sacc[mt][1]);
            }

            __syncthreads();   // B_k: all waves done reading K region (P overlays it)

            // ---- online softmax in raw units (scale folded into SCL2) ----
            const bool diag = (kt == qt);
            #pragma unroll
            for (int nt = 0; nt < 2; nt++) {
                const int q = q0 + nt * 16 + ln;
                float mx = m[nt];
                #pragma unroll
                for (int mt = 0; mt < 8; mt++)
                    #pragma unroll
                    for (int r = 0; r < 4; r++) {
                        float v = sacc[mt][nt][r];
                        if (diag && (k0 + mt * 16 + qq * 4 + r > q)) v = -3e38f;
                        sacc[mt][nt][r] = v;
                        mx = fmaxf(mx, v);
                    }
                mx = fmaxf(mx, __shfl_xor(mx, 16));
                mx = fmaxf(mx, __shfl_xor(mx, 32));
                float alpha = exp2f((m[nt] - mx) * SCL2);
                m[nt] = mx;
                float rs = 0.f;
                #pragma unroll
                for (int mt = 0; mt < 8; mt++) {
                    float p0 = exp2f((sacc[mt][nt][0] - mx) * SCL2);
                    float p1 = exp2f((sacc[mt][nt][1] - mx) * SCL2);
                    float p2 = exp2f((sacc[mt][nt][2] - mx) * SCL2);
                    float p3 = exp2f((sacc[mt][nt][3] - mx) * SCL2);
                    rs += (p0 + p1) + (p2 + p3);
                    us4 pu = { f2bf(p0), f2bf(p1), f2bf(p2), f2bf(p3) };
                    // P[q][key]: row q=nt*16+ln, key-unit mt*2+(qq>>1), swizzle ^ln
                    *(us4*)&Pseg[(nt * 16 + ln) * 128 + ((mt * 2 + (qq >> 1)) ^ ln) * 8 + (qq & 1) * 4] = pu;
                }
                rs += __shfl_xor(rs, 16);
                rs += __shfl_xor(rs, 32);
                l[nt] = l[nt] * alpha + rs;
                #pragma unroll
                for (int mt = 0; mt < 8; mt++)
                    #pragma unroll
                    for (int r = 0; r < 4; r++)
                        oacc[mt][nt][r] *= alpha;
            }

            // ---- O^T += V^T P^T : A = V^T frags, B = P frags (both LDS) ----
            bf16x8 pf[4][2];
            #pragma unroll
            for (int ks = 0; ks < 4; ks++)
                #pragma unroll
                for (int nt = 0; nt < 2; nt++)
                    pf[ks][nt] = *(const bf16x8*)&Pseg[(nt * 16 + ln) * 128 + ((ks * 4 + qq) ^ ln) * 8];
            #pragma unroll
            for (int mt = 0; mt < 8; mt++) {
                const unsigned short* vr = &KV[16384 + (mt * 16 + ln) * 128];
                bf16x8 vf0 = *(const bf16x8*)&vr[((0 + qq) ^ ln) * 8];
                bf16x8 vf1 = *(const bf16x8*)&vr[((4 + qq) ^ ln) * 8];
                bf16x8 vf2 = *(const bf16x8*)&vr[((8 + qq) ^ ln) * 8];
                bf16x8 vf3 = *(const bf16x8*)&vr[((12 + qq) ^ ln) * 8];
                oacc[mt][0] = MFMA(vf0, pf[0][0], oacc[mt][0]);
                oacc[mt][1] = MFMA(vf0, pf[0][1], oacc[mt][1]);
                oacc[mt][0] = MFMA(vf1, pf[1][0], oacc[mt][0]);
                oacc[mt][1] = MFMA(vf1, pf[1][1], oacc[mt][1]);
                oacc[mt][0] = MFMA(vf2, pf[2][0], oacc[mt][0]);
                oacc[mt][1] = MFMA(vf2, pf[2][1], oacc[mt][1]);
                oacc[mt][0] = MFMA(vf3, pf[3][0], oacc[mt][0]);
                oacc[mt][1] = MFMA(vf3, pf[3][1], oacc[mt][1]);
            }
        }

        // ---- epilogue: lane owns column q; d = mt*16 + qq*4 + r ----
        #pragma unroll
        for (int nt = 0; nt < 2; nt++) {
            const int q = q0 + nt * 16 + ln;
            float inv = 1.f / l[nt];
            unsigned short* ao = aout + ((long)b * SEQ + q) * DIM + h * HDIM;
            #pragma unroll
            for (int mt = 0; mt < 8; mt++) {
                us4 o = { f2bf(oacc[mt][nt][0] * inv), f2bf(oacc[mt][nt][1] * inv),
                          f2bf(oacc[mt][nt][2] * inv), f2bf(oacc[mt][nt][3] * inv) };
                *(us4*)&ao[mt * 16 + qq * 4] = o;
            }
        }
    }
}

// ---------------------------------------------------------------------------
// Output GEMM (unchanged): d_out[8192 x 2048] f32 = attn * wo_t
// ---------------------------------------------------------------------------
__launch_bounds__(256, 2)
__global__ void out_gemm(const unsigned short* __restrict__ ab,
                         const unsigned short* __restrict__ wt,
                         float* __restrict__ out) {
    constexpr int K = DIM;
    __shared__ __align__(16) unsigned short As[128 * 32];
    __shared__ __align__(16) unsigned short Bs[128 * 32];
    const int tid = threadIdx.x;
    const int m0 = blockIdx.y * 128;
    const int n0 = blockIdx.x * 128;
    const int w = tid >> 6, lane = tid & 63, qq = lane >> 4, ln = lane & 15;
    const int wm = w >> 1, wn = w & 1;

    f32x4 acc[4][4] = {};

    const int arow = tid >> 2;
    const int acol = (tid & 3) * 8;
    const unsigned short* ag = ab + (long)(m0 + arow) * K + acol;
    const unsigned short* bg = wt + (long)(n0 + arow) * K + acol;
    unsigned short* al = As + tid * 8;
    unsigned short* bl = Bs + tid * 8;

    for (int kk = 0; kk < K; kk += 32) {
        __syncthreads();
        stage16(ag + kk, al);
        stage16(ag + kk + 64 * K, al + 2048);
        stage16(bg + kk, bl);
        stage16(bg + kk + 64 * K, bl + 2048);
        __syncthreads();
        bf16x8 a[4], b[4];
        for (int mt = 0; mt < 4; mt++)
            a[mt] = *(const bf16x8*)&As[(wm * 64 + mt * 16 + ln) * 32 + qq * 8];
        for (int nt = 0; nt < 4; nt++)
            b[nt] = *(const bf16x8*)&Bs[(wn * 64 + nt * 16 + ln) * 32 + qq * 8];
        for (int mt = 0; mt < 4; mt++)
            for (int nt = 0; nt < 4; nt++)
                acc[mt][nt] = MFMA(a[mt], b[nt], acc[mt][nt]);
    }

    for (int mt = 0; mt < 4; mt++)
        for (int nt = 0; nt < 4; nt++) {
            int n = n0 + wn * 64 + nt * 16 + ln;
            for (int r = 0; r < 4; r++) {
                int m = m0 + wm * 64 + mt * 16 + qq * 4 + r;
                out[(long)m * DIM + n] = acc[mt][nt][r];
            }
        }
}

// ---------------------------------------------------------------------------
// Workspace layout: see R1 (unchanged), total 176,160,768 bytes
// ---------------------------------------------------------------------------
extern "C" void kernel_launch(void* const* d_in, const int* in_sizes, int n_in,
                              void* d_out, int out_size, void* d_ws, size_t ws_size,
                              hipStream_t stream) {
    const float* x    = (const float*)d_in[0];
    const float* wq   = (const float*)d_in[1];
    const float* wk   = (const float*)d_in[2];
    const float* wv   = (const float*)d_in[3];
    const float* wo   = (const float*)d_in[4];
    const float* pcos = (const float*)d_in[5];
    const float* psin = (const float*)d_in[6];
    float* out = (float*)d_out;

    char* ws = (char*)d_ws;
    unsigned short* xb    = (unsigned short*)(ws);
    unsigned short* wqkvt = (unsigned short*)(ws + 33554432L);
    unsigned short* wot   = (unsigned short*)(ws + 50331648L);
    unsigned short* qbuf  = (unsigned short*)(ws + 58720256L);
    unsigned short* kbuf  = (unsigned short*)(ws + 92274688L);
    unsigned short* vbuf  = (unsigned short*)(ws + 109051904L);
    unsigned short* vtb   = (unsigned short*)(ws + 125829120L);
    unsigned short* aout  = (unsigned short*)(ws + 142606336L);

    conv_x<<<16384, 256, 0, stream>>>(x, xb);
    transpose_w<<<dim3(64, 64), dim3(32, 8), 0, stream>>>(wq, wqkvt, 2048, 0);
    transpose_w<<<dim3(32, 64), dim3(32, 8), 0, stream>>>(wk, wqkvt, 1024, 2048);
    transpose_w<<<dim3(32, 64), dim3(32, 8), 0, stream>>>(wv, wqkvt, 1024, 3072);
    transpose_w<<<dim3(64, 64), dim3(32, 8), 0, stream>>>(wo, wot, 2048, 0);

    qkv_gemm<<<dim3(32, 64), 256, 0, stream>>>(xb, wqkvt, pcos, psin, qbuf, kbuf, vbuf);
    transpose_v<<<dim3(4, 64, 32), dim3(32, 8), 0, stream>>>(vbuf, vtb);
    flash<<<dim3(8, 16, 4), 256, 0, stream>>>(qbuf, kbuf, vtb, aout);
    out_gemm<<<dim3(16, 64), 256, 0, stream>>>(aout, wot, out);
}

// Round 6
// 516.143 us; speedup vs baseline: 1.7603x; 1.0843x over previous
//
#include <hip/hip_runtime.h>
#include <stdint.h>

// ---------------------------------------------------------------------------
// Problem constants: B=4, S=2048, D=2048, H=16, KVH=8, HD=128, N_REP=2
// ---------------------------------------------------------------------------
#define SEQ   2048
#define DIM   2048
#define NH    16
#define NKVH  8
#define HDIM  128
#define MTOT  8192      // B*S
#define LOG2E 1.44269504088896340736f

typedef short bf16x8 __attribute__((ext_vector_type(8)));   // 8 bf16 = 4 VGPRs
typedef float f32x4  __attribute__((ext_vector_type(4)));
typedef unsigned short us4 __attribute__((ext_vector_type(4)));

#define MFMA(a, b, c) __builtin_amdgcn_mfma_f32_16x16x32_bf16((a), (b), (c), 0, 0, 0)

__device__ inline unsigned short f2bf(float f) {
    unsigned u = __builtin_bit_cast(unsigned, f);
    u = (u + 0x7FFFu + ((u >> 16) & 1u)) >> 16;   // RNE
    return (unsigned short)u;
}

__device__ inline void stage16(const void* g, void* l) {
    __builtin_amdgcn_global_load_lds(
        (const __attribute__((address_space(1))) void*)g,
        (__attribute__((address_space(3))) void*)l,
        16, 0, 0);
}

// ---------------------------------------------------------------------------
// Prep: x f32 -> bf16
// ---------------------------------------------------------------------------
__global__ void conv_x(const float* __restrict__ x, unsigned short* __restrict__ xb) {
    long i = ((long)blockIdx.x * 256 + threadIdx.x) * 4;
    float4 v = *(const float4*)(x + i);
    us4 o = { f2bf(v.x), f2bf(v.y), f2bf(v.z), f2bf(v.w) };
    *(us4*)(xb + i) = o;
}

// ---------------------------------------------------------------------------
// Prep: weight (K=2048 rows x N cols, f32) -> transposed bf16 [N][2048]
// ---------------------------------------------------------------------------
__global__ void transpose_w(const float* __restrict__ in, unsigned short* __restrict__ out,
                            int N, int row_off) {
    __shared__ float t[32][33];
    int tx = threadIdx.x, ty = threadIdx.y;
    int n0 = blockIdx.x * 32, k0 = blockIdx.y * 32;
    for (int i = 0; i < 4; i++)
        t[ty + i * 8][tx] = in[(long)(k0 + ty + i * 8) * N + n0 + tx];
    __syncthreads();
    for (int i = 0; i < 4; i++)
        out[(long)(row_off + n0 + ty + i * 8) * 2048 + k0 + tx] = f2bf(t[tx][ty + i * 8]);
}

// ---------------------------------------------------------------------------
// Prep: V (b,kvh,s,hd) bf16 -> V^T (b,kvh,hd,s) bf16
// ---------------------------------------------------------------------------
__global__ void transpose_v(const unsigned short* __restrict__ v, unsigned short* __restrict__ vt) {
    __shared__ unsigned short t[32][33];
    int tx = threadIdx.x, ty = threadIdx.y;
    int d0 = blockIdx.x * 32, s0 = blockIdx.y * 32, bk = blockIdx.z;
    const unsigned short* vin = v + (long)bk * SEQ * HDIM;
    unsigned short* vo = vt + (long)bk * HDIM * SEQ;
    for (int i = 0; i < 4; i++)
        t[ty + i * 8][tx] = vin[(long)(s0 + ty + i * 8) * HDIM + d0 + tx];
    __syncthreads();
    for (int i = 0; i < 4; i++)
        vo[(long)(d0 + ty + i * 8) * SEQ + s0 + tx] = t[tx][ty + i * 8];
}

// ---------------------------------------------------------------------------
// QKV GEMM v3: BK=64 (32 k-iters, half the barrier drains of BK=32),
// XOR-swizzled LDS (16B unit j of row r at j^(r&7): conflict-free frag reads,
// staging stays lane-contiguous + globally coalesced).  C^T MFMA orientation:
// reg dim = 4 consecutive d, lane dim = (b,s).  In-lane RoPE epilogue,
// aligned us4 stores, block-uniform branches.
// ---------------------------------------------------------------------------
__launch_bounds__(256, 2)
__global__ void qkv_gemm(const unsigned short* __restrict__ xb,
                         const unsigned short* __restrict__ wt,
                         const float* __restrict__ pcos, const float* __restrict__ psin,
                         unsigned short* __restrict__ qb, unsigned short* __restrict__ kbuf,
                         unsigned short* __restrict__ vbuf) {
    constexpr int K = DIM;
    __shared__ __align__(16) unsigned short As[128 * 64];
    __shared__ __align__(16) unsigned short Bs[128 * 64];
    const int tid = threadIdx.x;
    const int m0 = blockIdx.y * 128;
    const int n0 = blockIdx.x * 128;
    const int w = tid >> 6, lane = tid & 63, qq = lane >> 4, ln = lane & 15;
    const int wm = w >> 1, wn = w & 1;

    f32x4 acc[4][4] = {};

    const int arow = tid >> 3;                          // 0..31 (row within 32-row round)
    const int aswz = ((tid & 7) ^ (arow & 7)) * 8;      // swizzled source col (shorts)
    const unsigned short* ag = xb + (long)(m0 + arow) * K + aswz;
    const unsigned short* bg = wt + (long)(n0 + arow) * K + aswz;
    unsigned short* al = As + tid * 8;
    unsigned short* bl = Bs + tid * 8;

    for (int kk = 0; kk < K; kk += 64) {
        __syncthreads();
        stage16(ag + kk,          al);
        stage16(ag + kk + 32 * K, al + 2048);
        stage16(ag + kk + 64 * K, al + 4096);
        stage16(ag + kk + 96 * K, al + 6144);
        stage16(bg + kk,          bl);
        stage16(bg + kk + 32 * K, bl + 2048);
        stage16(bg + kk + 64 * K, bl + 4096);
        stage16(bg + kk + 96 * K, bl + 6144);
        __syncthreads();
        bf16x8 a[2][4], b[2][4];
        for (int ks = 0; ks < 2; ks++) {
            for (int mt = 0; mt < 4; mt++)
                a[ks][mt] = *(const bf16x8*)&As[(wm * 64 + mt * 16 + ln) * 64 + (((ks * 4 + qq) ^ (ln & 7)) * 8)];
            for (int nt = 0; nt < 4; nt++)
                b[ks][nt] = *(const bf16x8*)&Bs[(wn * 64 + nt * 16 + ln) * 64 + (((ks * 4 + qq) ^ (ln & 7)) * 8)];
        }
        for (int ks = 0; ks < 2; ks++)
            for (int mt = 0; mt < 4; mt++)
                for (int nt = 0; nt < 4; nt++)
                    acc[mt][nt] = MFMA(b[ks][nt], a[ks][mt], acc[mt][nt]);   // C^T
    }

    // epilogue: n = n0 + wn*64 + nt*16 + qq*4 + r (regs), m = m0 + wm*64 + mt*16 + ln
    const bool isv = (n0 >= 3072);          // block-uniform: no RoPE for v
    for (int mt = 0; mt < 4; mt++) {
        int m = m0 + wm * 64 + mt * 16 + ln;
        int b_ = m >> 11, s = m & (SEQ - 1);
        const float* crow = pcos + s * 64;
        const float* srow = psin + s * 64;
        for (int nt = 0; nt < 4; nt++) {
            int n = n0 + wn * 64 + nt * 16 + qq * 4;
            int d = n & (HDIM - 1);
            f32x4 v = acc[mt][nt];
            float o0, o1, o2, o3;
            if (!isv) {                      // RoPE, pairs in-lane
                int i = d >> 1;
                float2 cc = *(const float2*)(crow + i);
                float2 ss = *(const float2*)(srow + i);
                o0 = v[0] * cc.x - v[1] * ss.x;
                o1 = v[0] * ss.x + v[1] * cc.x;
                o2 = v[2] * cc.y - v[3] * ss.y;
                o3 = v[2] * ss.y + v[3] * cc.y;
            } else {
                o0 = v[0]; o1 = v[1]; o2 = v[2]; o3 = v[3];
            }
            us4 pu = { f2bf(o0), f2bf(o1), f2bf(o2), f2bf(o3) };
            if (n < 2048) {
                int hh = n >> 7;
                *(us4*)&qb[((long)(b_ * NH + hh) * SEQ + s) * HDIM + d] = pu;
            } else if (n < 3072) {
                int kvh = (n - 2048) >> 7;
                *(us4*)&kbuf[((long)(b_ * NKVH + kvh) * SEQ + s) * HDIM + d] = pu;
            } else {
                int kvh = (n - 3072) >> 7;
                *(us4*)&vbuf[((long)(b_ * NKVH + kvh) * SEQ + s) * HDIM + d] = pu;
            }
        }
    }
}

// ---------------------------------------------------------------------------
// Flash attention v3b (unchanged from R5): bulk async K/V staging, XOR
// swizzle, transposed math, P overlays K region per-wave.
// ---------------------------------------------------------------------------
__launch_bounds__(256, 2)
__global__ void flash(const unsigned short* __restrict__ qb,
                      const unsigned short* __restrict__ kb,
                      const unsigned short* __restrict__ vtb,
                      unsigned short* __restrict__ aout) {
    __shared__ __align__(16) unsigned short KV[32768];   // K: shorts [0,16384)  V^T: [16384,32768)
    const int tid = threadIdx.x;
    const int w = tid >> 6, lane = tid & 63, qq = lane >> 4, ln = lane & 15;
    unsigned short* Pseg = KV + w * 4096;                // P overlay, wave-private 8 KB

    // block swizzle: XCD = flat%8; pin 4 (b,kv) pairs per XCD
    int f = blockIdx.x + (blockIdx.y << 3) + (blockIdx.z << 7);  // grid (8,16,4)
    int xcd = f & 7, j = f >> 3;
    int bkv = xcd + 8 * (j & 3);
    int b = bkv >> 3, kv = bkv & 7;
    int rem = j >> 2;
    int h = kv * 2 + (rem & 1);
    int qpair = rem >> 1;

    const unsigned short* qbase = qb + (long)(b * NH + h) * SEQ * HDIM;
    const unsigned short* kbase = kb + (long)(b * NKVH + kv) * SEQ * HDIM;
    const unsigned short* vbase = vtb + (long)(b * NKVH + kv) * HDIM * SEQ;
    const float SCL2 = 0.088388347648318447f * LOG2E;   // scale * log2(e), folded

    const int srow = tid >> 4;                 // staging: row within 16-row group
    const int sswz = (tid & 15) ^ srow;        // staging: swizzled source unit

    for (int phase = 0; phase < 2; phase++) {
        const int qt = (phase == 0) ? qpair : 15 - qpair;
        const int q0 = qt * 128 + w * 32;

        // Q fragments (B-operand layout: lane=q, k-contiguous)
        bf16x8 qf[2][4];
        for (int nt = 0; nt < 2; nt++)
            for (int ks = 0; ks < 4; ks++)
                qf[nt][ks] = *(const bf16x8*)&qbase[(long)(q0 + nt * 16 + ln) * HDIM + ks * 32 + qq * 8];

        float m[2] = { -3e38f, -3e38f }, l[2] = { 0.f, 0.f };
        f32x4 oacc[8][2] = {};

        #pragma unroll 1
        for (int kt = 0; kt <= qt; kt++) {
            const int k0 = kt * 128;

            __syncthreads();   // B_pre: everyone done reading previous K/V/P
            // stage K [key][hd-unit^swz] and V^T [hd][key-unit^swz]
            char* kl = (char*)KV;
            #pragma unroll
            for (int r = 0; r < 8; r++) {
                int key = r * 16 + srow;
                stage16(kbase + (long)(k0 + key) * HDIM + sswz * 8, kl + r * 4096 + tid * 16);
            }
            #pragma unroll
            for (int r = 0; r < 8; r++) {
                int hd = r * 16 + srow;
                stage16(vbase + (long)hd * SEQ + k0 + sswz * 8, kl + 32768 + r * 4096 + tid * 16);
            }
            __syncthreads();   // B_vis: compiler's vmcnt(0) drain + visibility

            // ---- S^T = K Q^T : A-frags from swizzled LDS ----
            f32x4 sacc[8][2] = {};
            #pragma unroll
            for (int mt = 0; mt < 8; mt++) {
                const unsigned short* kr = &KV[(mt * 16 + ln) * 128];
                bf16x8 kf0 = *(const bf16x8*)&kr[((0 + qq) ^ ln) * 8];
                bf16x8 kf1 = *(const bf16x8*)&kr[((4 + qq) ^ ln) * 8];
                bf16x8 kf2 = *(const bf16x8*)&kr[((8 + qq) ^ ln) * 8];
                bf16x8 kf3 = *(const bf16x8*)&kr[((12 + qq) ^ ln) * 8];
                sacc[mt][0] = MFMA(kf0, qf[0][0], sacc[mt][0]);
                sacc[mt][1] = MFMA(kf0, qf[1][0], sacc[mt][1]);
                sacc[mt][0] = MFMA(kf1, qf[0][1], sacc[mt][0]);
                sacc[mt][1] = MFMA(kf1, qf[1][1], sacc[mt][1]);
                sacc[mt][0] = MFMA(kf2, qf[0][2], sacc[mt][0]);
                sacc[mt][1] = MFMA(kf2, qf[1][2], sacc[mt][1]);
                sacc[mt][0] = MFMA(kf3, qf[0][3], sacc[mt][0]);
                sacc[mt][1] = MFMA(kf3, qf[1][3], sacc[mt][1]);
            }

            __syncthreads();   // B_k: all waves done reading K region (P overlays it)

            // ---- online softmax in raw units (scale folded into SCL2) ----
            const bool diag = (kt == qt);
            #pragma unroll
            for (int nt = 0; nt < 2; nt++) {
                const int q = q0 + nt * 16 + ln;
                float mx = m[nt];
                #pragma unroll
                for (int mt = 0; mt < 8; mt++)
                    #pragma unroll
                    for (int r = 0; r < 4; r++) {
                        float v = sacc[mt][nt][r];
                        if (diag && (k0 + mt * 16 + qq * 4 + r > q)) v = -3e38f;
                        sacc[mt][nt][r] = v;
                        mx = fmaxf(mx, v);
                    }
                mx = fmaxf(mx, __shfl_xor(mx, 16));
                mx = fmaxf(mx, __shfl_xor(mx, 32));
                float alpha = exp2f((m[nt] - mx) * SCL2);
                m[nt] = mx;
                float rs = 0.f;
                #pragma unroll
                for (int mt = 0; mt < 8; mt++) {
                    float p0 = exp2f((sacc[mt][nt][0] - mx) * SCL2);
                    float p1 = exp2f((sacc[mt][nt][1] - mx) * SCL2);
                    float p2 = exp2f((sacc[mt][nt][2] - mx) * SCL2);
                    float p3 = exp2f((sacc[mt][nt][3] - mx) * SCL2);
                    rs += (p0 + p1) + (p2 + p3);
                    us4 pu = { f2bf(p0), f2bf(p1), f2bf(p2), f2bf(p3) };
                    // P[q][key]: row q=nt*16+ln, key-unit mt*2+(qq>>1), swizzle ^ln
                    *(us4*)&Pseg[(nt * 16 + ln) * 128 + ((mt * 2 + (qq >> 1)) ^ ln) * 8 + (qq & 1) * 4] = pu;
                }
                rs += __shfl_xor(rs, 16);
                rs += __shfl_xor(rs, 32);
                l[nt] = l[nt] * alpha + rs;
                #pragma unroll
                for (int mt = 0; mt < 8; mt++)
                    #pragma unroll
                    for (int r = 0; r < 4; r++)
                        oacc[mt][nt][r] *= alpha;
            }

            // ---- O^T += V^T P^T : A = V^T frags, B = P frags (both LDS) ----
            bf16x8 pf[4][2];
            #pragma unroll
            for (int ks = 0; ks < 4; ks++)
                #pragma unroll
                for (int nt = 0; nt < 2; nt++)
                    pf[ks][nt] = *(const bf16x8*)&Pseg[(nt * 16 + ln) * 128 + ((ks * 4 + qq) ^ ln) * 8];
            #pragma unroll
            for (int mt = 0; mt < 8; mt++) {
                const unsigned short* vr = &KV[16384 + (mt * 16 + ln) * 128];
                bf16x8 vf0 = *(const bf16x8*)&vr[((0 + qq) ^ ln) * 8];
                bf16x8 vf1 = *(const bf16x8*)&vr[((4 + qq) ^ ln) * 8];
                bf16x8 vf2 = *(const bf16x8*)&vr[((8 + qq) ^ ln) * 8];
                bf16x8 vf3 = *(const bf16x8*)&vr[((12 + qq) ^ ln) * 8];
                oacc[mt][0] = MFMA(vf0, pf[0][0], oacc[mt][0]);
                oacc[mt][1] = MFMA(vf0, pf[0][1], oacc[mt][1]);
                oacc[mt][0] = MFMA(vf1, pf[1][0], oacc[mt][0]);
                oacc[mt][1] = MFMA(vf1, pf[1][1], oacc[mt][1]);
                oacc[mt][0] = MFMA(vf2, pf[2][0], oacc[mt][0]);
                oacc[mt][1] = MFMA(vf2, pf[2][1], oacc[mt][1]);
                oacc[mt][0] = MFMA(vf3, pf[3][0], oacc[mt][0]);
                oacc[mt][1] = MFMA(vf3, pf[3][1], oacc[mt][1]);
            }
        }

        // ---- epilogue: lane owns column q; d = mt*16 + qq*4 + r ----
        #pragma unroll
        for (int nt = 0; nt < 2; nt++) {
            const int q = q0 + nt * 16 + ln;
            float inv = 1.f / l[nt];
            unsigned short* ao = aout + ((long)b * SEQ + q) * DIM + h * HDIM;
            #pragma unroll
            for (int mt = 0; mt < 8; mt++) {
                us4 o = { f2bf(oacc[mt][nt][0] * inv), f2bf(oacc[mt][nt][1] * inv),
                          f2bf(oacc[mt][nt][2] * inv), f2bf(oacc[mt][nt][3] * inv) };
                *(us4*)&ao[mt * 16 + qq * 4] = o;
            }
        }
    }
}

// ---------------------------------------------------------------------------
// Output GEMM v2: BK=64 + XOR swizzle (same staging as qkv v3), normal
// orientation epilogue (scalar f32 stores are lane-coalesced).
// ---------------------------------------------------------------------------
__launch_bounds__(256, 2)
__global__ void out_gemm(const unsigned short* __restrict__ ab,
                         const unsigned short* __restrict__ wt,
                         float* __restrict__ out) {
    constexpr int K = DIM;
    __shared__ __align__(16) unsigned short As[128 * 64];
    __shared__ __align__(16) unsigned short Bs[128 * 64];
    const int tid = threadIdx.x;
    const int m0 = blockIdx.y * 128;
    const int n0 = blockIdx.x * 128;
    const int w = tid >> 6, lane = tid & 63, qq = lane >> 4, ln = lane & 15;
    const int wm = w >> 1, wn = w & 1;

    f32x4 acc[4][4] = {};

    const int arow = tid >> 3;
    const int aswz = ((tid & 7) ^ (arow & 7)) * 8;
    const unsigned short* ag = ab + (long)(m0 + arow) * K + aswz;
    const unsigned short* bg = wt + (long)(n0 + arow) * K + aswz;
    unsigned short* al = As + tid * 8;
    unsigned short* bl = Bs + tid * 8;

    for (int kk = 0; kk < K; kk += 64) {
        __syncthreads();
        stage16(ag + kk,          al);
        stage16(ag + kk + 32 * K, al + 2048);
        stage16(ag + kk + 64 * K, al + 4096);
        stage16(ag + kk + 96 * K, al + 6144);
        stage16(bg + kk,          bl);
        stage16(bg + kk + 32 * K, bl + 2048);
        stage16(bg + kk + 64 * K, bl + 4096);
        stage16(bg + kk + 96 * K, bl + 6144);
        __syncthreads();
        bf16x8 a[2][4], b[2][4];
        for (int ks = 0; ks < 2; ks++) {
            for (int mt = 0; mt < 4; mt++)
                a[ks][mt] = *(const bf16x8*)&As[(wm * 64 + mt * 16 + ln) * 64 + (((ks * 4 + qq) ^ (ln & 7)) * 8)];
            for (int nt = 0; nt < 4; nt++)
                b[ks][nt] = *(const bf16x8*)&Bs[(wn * 64 + nt * 16 + ln) * 64 + (((ks * 4 + qq) ^ (ln & 7)) * 8)];
        }
        for (int ks = 0; ks < 2; ks++)
            for (int mt = 0; mt < 4; mt++)
                for (int nt = 0; nt < 4; nt++)
                    acc[mt][nt] = MFMA(a[ks][mt], b[ks][nt], acc[mt][nt]);
    }

    for (int mt = 0; mt < 4; mt++)
        for (int nt = 0; nt < 4; nt++) {
            int n = n0 + wn * 64 + nt * 16 + ln;
            for (int r = 0; r < 4; r++) {
                int m = m0 + wm * 64 + mt * 16 + qq * 4 + r;
                out[(long)m * DIM + n] = acc[mt][nt][r];
            }
        }
}

// ---------------------------------------------------------------------------
// Workspace layout: see R1 (unchanged), total 176,160,768 bytes
// ---------------------------------------------------------------------------
extern "C" void kernel_launch(void* const* d_in, const int* in_sizes, int n_in,
                              void* d_out, int out_size, void* d_ws, size_t ws_size,
                              hipStream_t stream) {
    const float* x    = (const float*)d_in[0];
    const float* wq   = (const float*)d_in[1];
    const float* wk   = (const float*)d_in[2];
    const float* wv   = (const float*)d_in[3];
    const float* wo   = (const float*)d_in[4];
    const float* pcos = (const float*)d_in[5];
    const float* psin = (const float*)d_in[6];
    float* out = (float*)d_out;

    char* ws = (char*)d_ws;
    unsigned short* xb    = (unsigned short*)(ws);
    unsigned short* wqkvt = (unsigned short*)(ws + 33554432L);
    unsigned short* wot   = (unsigned short*)(ws + 50331648L);
    unsigned short* qbuf  = (unsigned short*)(ws + 58720256L);
    unsigned short* kbuf  = (unsigned short*)(ws + 92274688L);
    unsigned short* vbuf  = (unsigned short*)(ws + 109051904L);
    unsigned short* vtb   = (unsigned short*)(ws + 125829120L);
    unsigned short* aout  = (unsigned short*)(ws + 142606336L);

    conv_x<<<16384, 256, 0, stream>>>(x, xb);
    transpose_w<<<dim3(64, 64), dim3(32, 8), 0, stream>>>(wq, wqkvt, 2048, 0);
    transpose_w<<<dim3(32, 64), dim3(32, 8), 0, stream>>>(wk, wqkvt, 1024, 2048);
    transpose_w<<<dim3(32, 64), dim3(32, 8), 0, stream>>>(wv, wqkvt, 1024, 3072);
    transpose_w<<<dim3(64, 64), dim3(32, 8), 0, stream>>>(wo, wot, 2048, 0);

    qkv_gemm<<<dim3(32, 64), 256, 0, stream>>>(xb, wqkvt, pcos, psin, qbuf, kbuf, vbuf);
    transpose_v<<<dim3(4, 64, 32), dim3(32, 8), 0, stream>>>(vbuf, vtb);
    flash<<<dim3(8, 16, 4), 256, 0, stream>>>(qbuf, kbuf, vtb, aout);
    out_gemm<<<dim3(16, 64), 256, 0, stream>>>(aout, wot, out);
}